// Round 1
// baseline (1635.038 us; speedup 1.0000x reference)
//
#include <hip/hip_runtime.h>
#include <hip/hip_bf16.h>
#include <math.h>

// Problem constants (match reference)
#define NNODES 20000
#define NEDGES 320000
#define INC 128
#define DMODEL 256
#define NHEAD 8
#define DHEAD 32
#define NLAYER 2
#define NBUCKET 64
#define DFF 512
#define ETOT (NEDGES + NNODES)

// ---------------------------------------------------------------------------
// Degree count
__global__ void count_deg_k(const int* __restrict__ row, int* __restrict__ deg, int E) {
    int e = blockIdx.x * 256 + threadIdx.x;
    if (e < E) atomicAdd(&deg[row[e]], 1);
}

// bucket = clip(floor(log2(max(deg,1))), 1, 63)
__global__ void bucket_k(const int* __restrict__ deg, int* __restrict__ bkt, int n) {
    int i = blockIdx.x * 256 + threadIdx.x;
    if (i < n) {
        int d = deg[i]; if (d < 1) d = 1;
        int b = 31 - __clz(d);
        b = min(max(b, 1), NBUCKET - 1);
        bkt[i] = b;
    }
}

// exclusive scan of (deg[i]+1) -> off[i]; off[n]=total; cur[i]=off[i]
__global__ __launch_bounds__(1024) void scan_offsets_k(const int* __restrict__ deg,
                                                       int* __restrict__ off,
                                                       int* __restrict__ cur, int n) {
    const int T = 1024;
    int t = threadIdx.x;
    int chunk = (n + T - 1) / T;
    int base = t * chunk;
    int s = 0;
    for (int i = 0; i < chunk; ++i) {
        int idx = base + i;
        if (idx < n) s += deg[idx] + 1;
    }
    __shared__ int ps[1024];
    ps[t] = s;
    __syncthreads();
    for (int d = 1; d < T; d <<= 1) {
        int v = (t >= d) ? ps[t - d] : 0;
        __syncthreads();
        ps[t] += v;
        __syncthreads();
    }
    int run = (t == 0) ? 0 : ps[t - 1];
    for (int i = 0; i < chunk; ++i) {
        int idx = base + i;
        if (idx < n) {
            off[idx] = run; cur[idx] = run;
            run += deg[idx] + 1;
        }
    }
    if (t == T - 1) off[n] = ps[T - 1];
}

// fill CSR columns: edges then self loops (order within a node irrelevant)
__global__ void csr_fill_k(const int* __restrict__ row, const int* __restrict__ col,
                           int* __restrict__ cur, int* __restrict__ csr, int E, int n) {
    int e = blockIdx.x * 256 + threadIdx.x;
    if (e < E) {
        int p = atomicAdd(&cur[row[e]], 1);
        csr[p] = col[e];
    } else if (e < E + n) {
        int nn = e - E;
        int p = atomicAdd(&cur[nn], 1);
        csr[p] = nn;
    }
}

// ---------------------------------------------------------------------------
// fp32 tiled GEMM:  C[M,Nout] = A[M,K] @ W[K,Nout] + bias[Nout] (+emb[bkt[m]])(+gelu)
// BM=BN=64, BK=32, 256 threads, 4x4 per thread.
__global__ __launch_bounds__(256) void gemm_ep_k(
        const float* __restrict__ A, const float* __restrict__ W,
        const float* __restrict__ bias, float* __restrict__ C,
        int M, int K, int Nout,
        const float* __restrict__ emb, const int* __restrict__ bkt, int act) {
    __shared__ __align__(16) float As[32][68];  // [k][m], padded
    __shared__ __align__(16) float Ws[32][68];  // [k][n], padded
    const int bm = blockIdx.x * 64;
    const int bn = blockIdx.y * 64;
    const int t  = threadIdx.x;
    const int tx = t & 15, ty = t >> 4;
    float acc[4][4] = {};
    for (int k0 = 0; k0 < K; k0 += 32) {
        #pragma unroll
        for (int i = 0; i < 8; ++i) {
            int idx = t + i * 256;
            int r = idx >> 5, c = idx & 31;
            float v = 0.f;
            if (bm + r < M) v = A[(size_t)(bm + r) * K + k0 + c];
            As[c][r] = v;
        }
        #pragma unroll
        for (int i = 0; i < 8; ++i) {
            int idx = t + i * 256;
            int r = idx >> 6, c = idx & 63;
            Ws[r][c] = W[(size_t)(k0 + r) * Nout + bn + c];
        }
        __syncthreads();
        #pragma unroll
        for (int k = 0; k < 32; ++k) {
            float a4[4], b4[4];
            *(float4*)a4 = *(const float4*)&As[k][ty * 4];
            *(float4*)b4 = *(const float4*)&Ws[k][tx * 4];
            #pragma unroll
            for (int i = 0; i < 4; ++i)
                #pragma unroll
                for (int j = 0; j < 4; ++j)
                    acc[i][j] = fmaf(a4[i], b4[j], acc[i][j]);
        }
        __syncthreads();
    }
    #pragma unroll
    for (int i = 0; i < 4; ++i) {
        int m = bm + ty * 4 + i;
        if (m >= M) continue;
        const float* erow = emb ? (emb + (size_t)bkt[m] * Nout) : nullptr;
        #pragma unroll
        for (int j = 0; j < 4; ++j) {
            int n = bn + tx * 4 + j;
            float v = acc[i][j] + bias[n];
            if (erow) v += erow[n];
            if (act) v = 0.5f * v * (1.f + erff(v * 0.70710678118654752f));
            C[(size_t)m * Nout + n] = v;
        }
    }
}

// ---------------------------------------------------------------------------
// Per-node attention: block = 256 threads = 8 heads x 32 dims, 1 node/block.
// Pass 1: scores (dot via shfl butterfly) -> LDS cache + running max.
// Pass 2: es accumulate, unnormalized agg, divide by sum at end.
#define SCAP 1024
__global__ __launch_bounds__(256) void attn_node_k(
        const float* __restrict__ Q, const float* __restrict__ K,
        const float* __restrict__ V,
        const int* __restrict__ off, const int* __restrict__ csr,
        const int* __restrict__ bkt, const float* __restrict__ sb_i,
        float* __restrict__ agg) {
    __shared__ float sc_lds[SCAP * NHEAD];  // 32 KB
    const int node = blockIdx.x;
    const int tid  = threadIdx.x;
    const int hh   = tid >> 5;
    const int d    = tid & 31;
    const int s0 = off[node], s1 = off[node + 1];
    const float q = Q[(size_t)node * DMODEL + tid];
    const float sbn = sb_i[bkt[node] * NHEAD + hh];
    const float scale = 0.17677669529663689f;  // 32^-0.5
    float m = -1e30f;
    for (int j = s0; j < s1; ++j) {
        int c = csr[j];
        float p = q * K[(size_t)c * DMODEL + tid];
        #pragma unroll
        for (int mk = 16; mk >= 1; mk >>= 1) p += __shfl_xor(p, mk);
        float sc = p * scale + sbn + sb_i[bkt[c] * NHEAD + hh];
        int jj = j - s0;
        if (jj < SCAP && d == 0) sc_lds[jj * NHEAD + hh] = sc;
        m = fmaxf(m, sc);
    }
    float s = 0.f, acc = 0.f;
    for (int j = s0; j < s1; ++j) {
        int c = csr[j];
        int jj = j - s0;
        float sc;
        if (jj < SCAP) {
            sc = sc_lds[jj * NHEAD + hh];
        } else {  // fallback recompute (unreachable for this graph size)
            float p = q * K[(size_t)c * DMODEL + tid];
            #pragma unroll
            for (int mk = 16; mk >= 1; mk >>= 1) p += __shfl_xor(p, mk);
            sc = p * scale + sbn + sb_i[bkt[c] * NHEAD + hh];
        }
        float es = __expf(sc - m);
        s += es;
        acc += es * V[(size_t)c * DMODEL + tid];
    }
    agg[(size_t)node * DMODEL + tid] = acc / fmaxf(s, 1e-12f);
}

// ---------------------------------------------------------------------------
// h = LN(h + add) * g + b ; one block (256 thr) per row, D=256
__global__ __launch_bounds__(256) void add_ln_k(float* __restrict__ h,
                                                const float* __restrict__ add,
                                                const float* __restrict__ g,
                                                const float* __restrict__ b) {
    const int r = blockIdx.x;
    const int t = threadIdx.x;
    float x = h[(size_t)r * DMODEL + t] + add[(size_t)r * DMODEL + t];
    __shared__ float red[4];
    float s = x;
    #pragma unroll
    for (int mk = 32; mk >= 1; mk >>= 1) s += __shfl_xor(s, mk);
    if ((t & 63) == 0) red[t >> 6] = s;
    __syncthreads();
    float mean = (red[0] + red[1] + red[2] + red[3]) * (1.f / DMODEL);
    float dx = x - mean;
    __syncthreads();
    float v = dx * dx;
    #pragma unroll
    for (int mk = 32; mk >= 1; mk >>= 1) v += __shfl_xor(v, mk);
    if ((t & 63) == 0) red[t >> 6] = v;
    __syncthreads();
    float var = (red[0] + red[1] + red[2] + red[3]) * (1.f / DMODEL);
    h[(size_t)r * DMODEL + t] = dx * rsqrtf(var + 1e-5f) * g[t] + b[t];
}

// ---------------------------------------------------------------------------
extern "C" void kernel_launch(void* const* d_in, const int* in_sizes, int n_in,
                              void* d_out, int out_size, void* d_ws, size_t ws_size,
                              hipStream_t stream) {
    const float* x      = (const float*)d_in[0];
    const int*   row    = (const int*)d_in[1];
    const int*   col    = (const int*)d_in[2];
    const float* Wx     = (const float*)d_in[3];
    const float* bx     = (const float*)d_in[4];
    const float* degemb = (const float*)d_in[5];
    const float* sb     = (const float*)d_in[6];
    const float* Wq     = (const float*)d_in[7];
    const float* bq     = (const float*)d_in[8];
    const float* Wk     = (const float*)d_in[9];
    const float* bk     = (const float*)d_in[10];
    const float* Wv     = (const float*)d_in[11];
    const float* bv     = (const float*)d_in[12];
    const float* Wo     = (const float*)d_in[13];
    const float* bo     = (const float*)d_in[14];
    const float* ln1g   = (const float*)d_in[15];
    const float* ln1b   = (const float*)d_in[16];
    const float* ln2g   = (const float*)d_in[17];
    const float* ln2b   = (const float*)d_in[18];
    const float* W1     = (const float*)d_in[19];
    const float* b1     = (const float*)d_in[20];
    const float* W2     = (const float*)d_in[21];
    const float* b2     = (const float*)d_in[22];

    const int Nn = NNODES, E = NEDGES;
    float* h = (float*)d_out;                 // N x D, lives in d_out

    // workspace arena
    float* ws = (float*)d_ws;
    const size_t NB = (size_t)Nn * DMODEL;    // 5.12M floats
    float* Qb  = ws;                          // N x D
    float* Kb  = ws + NB;                     // N x D
    float* Vb  = ws + 2 * NB;                 // N x D
    float* AGG = ws + 3 * NB;                 // N x D
    float* OUT = ws + 4 * NB;                 // N x D
    float* FFb = ws;                          // N x DFF  (aliases Q,K after attention)
    int* CSR = (int*)(ws + 5 * NB);           // ETOT
    int* OFF = CSR + ETOT;                    // N+1
    int* CUR = OFF + Nn + 1;                  // N
    int* DEG = CUR + Nn;                      // N
    int* BKT = DEG + Nn;                      // N

    // ---- graph preprocessing ----
    hipMemsetAsync(DEG, 0, Nn * sizeof(int), stream);
    count_deg_k<<<(E + 255) / 256, 256, 0, stream>>>(row, DEG, E);
    bucket_k<<<(Nn + 255) / 256, 256, 0, stream>>>(DEG, BKT, Nn);
    scan_offsets_k<<<1, 1024, 0, stream>>>(DEG, OFF, CUR, Nn);
    csr_fill_k<<<(E + Nn + 255) / 256, 256, 0, stream>>>(row, col, CUR, CSR, E, Nn);

    // ---- embedding: h = x @ Wx + bx + deg_emb[bucket] ----
    {
        dim3 grid((Nn + 63) / 64, DMODEL / 64);
        gemm_ep_k<<<grid, 256, 0, stream>>>(x, Wx, bx, h, Nn, INC, DMODEL, degemb, BKT, 0);
    }

    // ---- layers ----
    for (int l = 0; l < NLAYER; ++l) {
        const float* Wq_i = Wq + (size_t)l * DMODEL * DMODEL;
        const float* Wk_i = Wk + (size_t)l * DMODEL * DMODEL;
        const float* Wv_i = Wv + (size_t)l * DMODEL * DMODEL;
        const float* Wo_i = Wo + (size_t)l * DMODEL * DMODEL;
        const float* bq_i = bq + (size_t)l * DMODEL;
        const float* bk_i = bk + (size_t)l * DMODEL;
        const float* bv_i = bv + (size_t)l * DMODEL;
        const float* bo_i = bo + (size_t)l * DMODEL;
        const float* sb_i = sb + (size_t)l * NBUCKET * NHEAD;
        const float* W1_i = W1 + (size_t)l * DMODEL * DFF;
        const float* b1_i = b1 + (size_t)l * DFF;
        const float* W2_i = W2 + (size_t)l * DFF * DMODEL;
        const float* b2_i = b2 + (size_t)l * DMODEL;

        dim3 gD((Nn + 63) / 64, DMODEL / 64);
        dim3 gF((Nn + 63) / 64, DFF / 64);

        gemm_ep_k<<<gD, 256, 0, stream>>>(h, Wq_i, bq_i, Qb, Nn, DMODEL, DMODEL, nullptr, nullptr, 0);
        gemm_ep_k<<<gD, 256, 0, stream>>>(h, Wk_i, bk_i, Kb, Nn, DMODEL, DMODEL, nullptr, nullptr, 0);
        gemm_ep_k<<<gD, 256, 0, stream>>>(h, Wv_i, bv_i, Vb, Nn, DMODEL, DMODEL, nullptr, nullptr, 0);

        attn_node_k<<<Nn, 256, 0, stream>>>(Qb, Kb, Vb, OFF, CSR, BKT, sb_i, AGG);

        gemm_ep_k<<<gD, 256, 0, stream>>>(AGG, Wo_i, bo_i, OUT, Nn, DMODEL, DMODEL, nullptr, nullptr, 0);
        add_ln_k<<<Nn, 256, 0, stream>>>(h, OUT, ln1g + (size_t)l * DMODEL, ln1b + (size_t)l * DMODEL);

        gemm_ep_k<<<gF, 256, 0, stream>>>(h, W1_i, b1_i, FFb, Nn, DMODEL, DFF, nullptr, nullptr, 1);
        gemm_ep_k<<<gD, 256, 0, stream>>>(FFb, W2_i, b2_i, OUT, Nn, DFF, DMODEL, nullptr, nullptr, 0);
        add_ln_k<<<Nn, 256, 0, stream>>>(h, OUT, ln2g + (size_t)l * DMODEL, ln2b + (size_t)l * DMODEL);
    }
}

// Round 5
// 831.420 us; speedup vs baseline: 1.9666x; 1.9666x over previous
//
#include <hip/hip_runtime.h>
#include <hip/hip_bf16.h>
#include <math.h>

#define NNODES 20000
#define NEDGES 320000
#define INC 128
#define DMODEL 256
#define NHEAD 8
#define DHEAD 32
#define NLAYER 2
#define NBUCKET 64
#define DFF 512
#define ETOT (NEDGES + NNODES)
#define SCAP 512

typedef __attribute__((ext_vector_type(8))) short short8v;
typedef __attribute__((ext_vector_type(4))) float f32x4;

__device__ __forceinline__ float bf2f(unsigned short u) {
    return __uint_as_float(((unsigned int)u) << 16);
}
__device__ __forceinline__ unsigned short f2bf(float f) {
    unsigned int u = __float_as_uint(f);
    unsigned int r = (u + 0x7FFFu + ((u >> 16) & 1u)) >> 16;
    return (unsigned short)r;
}

// ---------------------------------------------------------------------------
// Graph preprocessing
__global__ void count_deg_k(const int* __restrict__ row, int* __restrict__ deg, int E) {
    int e = blockIdx.x * 256 + threadIdx.x;
    if (e < E) atomicAdd(&deg[row[e]], 1);
}

__global__ void bucket_k(const int* __restrict__ deg, int* __restrict__ bkt, int n) {
    int i = blockIdx.x * 256 + threadIdx.x;
    if (i < n) {
        int d = deg[i]; if (d < 1) d = 1;
        int b = 31 - __clz(d);
        b = min(max(b, 1), NBUCKET - 1);
        bkt[i] = b;
    }
}

__global__ __launch_bounds__(1024) void scan_offsets_k(const int* __restrict__ deg,
                                                       int* __restrict__ off,
                                                       int* __restrict__ cur, int n) {
    const int T = 1024;
    int t = threadIdx.x;
    int chunk = (n + T - 1) / T;
    int base = t * chunk;
    int s = 0;
    for (int i = 0; i < chunk; ++i) {
        int idx = base + i;
        if (idx < n) s += deg[idx] + 1;
    }
    __shared__ int ps[1024];
    ps[t] = s;
    __syncthreads();
    for (int d = 1; d < T; d <<= 1) {
        int v = (t >= d) ? ps[t - d] : 0;
        __syncthreads();
        ps[t] += v;
        __syncthreads();
    }
    int run = (t == 0) ? 0 : ps[t - 1];
    for (int i = 0; i < chunk; ++i) {
        int idx = base + i;
        if (idx < n) {
            off[idx] = run; cur[idx] = run;
            run += deg[idx] + 1;
        }
    }
    if (t == T - 1) off[n] = ps[T - 1];
}

__global__ void csr_fill_k(const int* __restrict__ row, const int* __restrict__ col,
                           int* __restrict__ cur, int* __restrict__ csr, int E, int n) {
    int e = blockIdx.x * 256 + threadIdx.x;
    if (e < E) {
        int p = atomicAdd(&cur[row[e]], 1);
        csr[p] = col[e];
    } else if (e < E + n) {
        int nn = e - E;
        int p = atomicAdd(&cur[nn], 1);
        csr[p] = nn;
    }
}

// ---------------------------------------------------------------------------
// fp32 -> bf16 elementwise convert (4 elems/thread)
__global__ void cvt_bf16_k(const float* __restrict__ s, unsigned short* __restrict__ d, int n) {
    int i = (blockIdx.x * 256 + threadIdx.x) * 4;
    if (i < n) {
        float4 v = *(const float4*)(s + i);
        ushort4 o;
        o.x = f2bf(v.x); o.y = f2bf(v.y); o.z = f2bf(v.z); o.w = f2bf(v.w);
        *(ushort4*)(d + i) = o;
    }
}

// transpose + convert: src fp32 [K][N] -> dst bf16 [N][K]. K,N multiples of 32.
__global__ __launch_bounds__(256) void transpose_cvt_k(const float* __restrict__ src,
                                                       unsigned short* __restrict__ dst,
                                                       int K, int N) {
    __shared__ float tile[32][33];
    const int k0 = blockIdx.y * 32;
    const int n0 = blockIdx.x * 32;
    const int t = threadIdx.x;
    {
        int r = t >> 3, c = (t & 7) * 4;
        float4 v = *(const float4*)(src + (size_t)(k0 + r) * N + n0 + c);
        tile[r][c] = v.x; tile[r][c + 1] = v.y; tile[r][c + 2] = v.z; tile[r][c + 3] = v.w;
    }
    __syncthreads();
    {
        int n = t >> 3, k = (t & 7) * 4;
        ushort4 o;
        o.x = f2bf(tile[k][n]); o.y = f2bf(tile[k + 1][n]);
        o.z = f2bf(tile[k + 2][n]); o.w = f2bf(tile[k + 3][n]);
        *(ushort4*)(dst + (size_t)(n0 + n) * K + k0 + k) = o;
    }
}

__global__ void concat3_k(const float* a, const float* b, const float* c, float* d) {
    int t = blockIdx.x * 256 + threadIdx.x;
    if (t < 256) d[t] = a[t];
    else if (t < 512) d[t] = b[t - 256];
    else if (t < 768) d[t] = c[t - 512];
}

// ---------------------------------------------------------------------------
// bf16 MFMA GEMM: C[M,Nout] = A[M,K](bf16) @ Wt[Nout,K](bf16)^T + bias
//   optional: += emb[bkt[m]][n] ; optional gelu ; store fp32 (Cf) and/or bf16 (Cb)
// BM=BN=128, BK=32, 256 threads = 4 waves (2x2), wave tile 64x64 = 4x4 frags.
__global__ __launch_bounds__(256) void gemm_bf16_k(
        const unsigned short* __restrict__ A, const unsigned short* __restrict__ Wt,
        const float* __restrict__ bias,
        float* __restrict__ Cf, unsigned short* __restrict__ Cb,
        int M, int K, int Nout,
        const float* __restrict__ emb, const int* __restrict__ bkt, int act) {
    __shared__ unsigned short As[128 * 40];  // row stride 40 (pad 32->40): bank-spread
    __shared__ unsigned short Bs[128 * 40];
    const int bm = blockIdx.x * 128;
    const int bn = blockIdx.y * 128;
    const int t = threadIdx.x;
    const int wid = t >> 6, lane = t & 63;
    const int wm = wid >> 1, wn = wid & 1;
    const int l16 = lane & 15, kslc = lane >> 4;

    f32x4 acc[4][4] = {};

    const int mrow = t >> 1, half = t & 1;
    for (int k0 = 0; k0 < K; k0 += 32) {
        {
            const unsigned short* srcA = A + (size_t)(bm + mrow) * K + k0 + half * 16;
            uint4 v0 = {0, 0, 0, 0}, v1 = {0, 0, 0, 0};
            if (bm + mrow < M) {
                v0 = *(const uint4*)srcA;
                v1 = *(const uint4*)(srcA + 8);
            }
            *(uint4*)(&As[mrow * 40 + half * 16]) = v0;
            *(uint4*)(&As[mrow * 40 + half * 16 + 8]) = v1;
            const unsigned short* srcB = Wt + (size_t)(bn + mrow) * K + k0 + half * 16;
            *(uint4*)(&Bs[mrow * 40 + half * 16]) = *(const uint4*)srcB;
            *(uint4*)(&Bs[mrow * 40 + half * 16 + 8]) = *(const uint4*)(srcB + 8);
        }
        __syncthreads();
        short8v a[4], b[4];
        #pragma unroll
        for (int f = 0; f < 4; ++f) {
            a[f] = *(const short8v*)(&As[(wm * 64 + f * 16 + l16) * 40 + kslc * 8]);
            b[f] = *(const short8v*)(&Bs[(wn * 64 + f * 16 + l16) * 40 + kslc * 8]);
        }
        #pragma unroll
        for (int fm = 0; fm < 4; ++fm)
            #pragma unroll
            for (int fn = 0; fn < 4; ++fn)
                acc[fm][fn] = __builtin_amdgcn_mfma_f32_16x16x32_bf16(
                    a[fm], b[fn], acc[fm][fn], 0, 0, 0);
        __syncthreads();
    }

    // epilogue: C/D layout col=lane&15, row=(lane>>4)*4+reg
    #pragma unroll
    for (int fm = 0; fm < 4; ++fm) {
        #pragma unroll
        for (int fn = 0; fn < 4; ++fn) {
            int cc = wn * 64 + fn * 16 + l16;
            int gn = bn + cc;
            float bn_v = bias[gn];
            int rbase = bm + wm * 64 + fm * 16 + (lane >> 4) * 4;
            #pragma unroll
            for (int r = 0; r < 4; ++r) {
                int gm = rbase + r;
                if (gm >= M) continue;
                float v = acc[fm][fn][r] + bn_v;
                if (emb) v += emb[(size_t)bkt[gm] * Nout + gn];
                if (act) v = 0.5f * v * (1.f + erff(v * 0.70710678118654752f));
                if (Cf) Cf[(size_t)gm * Nout + gn] = v;
                if (Cb) Cb[(size_t)gm * Nout + gn] = f2bf(v);
            }
        }
    }
}

// ---------------------------------------------------------------------------
// Attention over CSR, bf16 Q/K/V packed as QKV[node][768] (Q|K|V).
// Block = 128 threads: head hh = t>>4 (8 heads), dim pair d2 = t&15 (16x2=32 dims).
__global__ __launch_bounds__(128) void attn_bf16_k(
        const unsigned short* __restrict__ QKV,
        const int* __restrict__ off, const int* __restrict__ csr,
        const int* __restrict__ bkt, const float* __restrict__ sb_i,
        unsigned short* __restrict__ aggb) {
    __shared__ float sc_lds[SCAP * NHEAD];  // 16 KB
    const int node = blockIdx.x;
    const int t = threadIdx.x;
    const int hh = t >> 4, d2 = t & 15;
    const int s0 = off[node], s1 = off[node + 1];
    const ushort2 q2 = *(const ushort2*)(QKV + (size_t)node * 768 + hh * 32 + d2 * 2);
    const float qx = bf2f(q2.x), qy = bf2f(q2.y);
    const float sbn = sb_i[bkt[node] * NHEAD + hh];
    const float scale = 0.17677669529663689f;  // 32^-0.5
    float m = -1e30f;
    for (int j = s0; j < s1; ++j) {
        int c = csr[j];
        ushort2 k2 = *(const ushort2*)(QKV + (size_t)c * 768 + 256 + hh * 32 + d2 * 2);
        float p = qx * bf2f(k2.x) + qy * bf2f(k2.y);
        #pragma unroll
        for (int mk = 8; mk >= 1; mk >>= 1) p += __shfl_xor(p, mk);
        float sc = p * scale + sbn + sb_i[bkt[c] * NHEAD + hh];
        int jj = j - s0;
        if (jj < SCAP && d2 == 0) sc_lds[jj * NHEAD + hh] = sc;
        m = fmaxf(m, sc);
    }
    float s = 0.f, ax = 0.f, ay = 0.f;
    for (int j = s0; j < s1; ++j) {
        int c = csr[j];
        int jj = j - s0;
        float sc;
        if (jj < SCAP) {
            sc = sc_lds[jj * NHEAD + hh];
        } else {
            ushort2 k2 = *(const ushort2*)(QKV + (size_t)c * 768 + 256 + hh * 32 + d2 * 2);
            float p = qx * bf2f(k2.x) + qy * bf2f(k2.y);
            #pragma unroll
            for (int mk = 8; mk >= 1; mk >>= 1) p += __shfl_xor(p, mk);
            sc = p * scale + sbn + sb_i[bkt[c] * NHEAD + hh];
        }
        float es = __expf(sc - m);
        s += es;
        ushort2 v2 = *(const ushort2*)(QKV + (size_t)c * 768 + 512 + hh * 32 + d2 * 2);
        ax += es * bf2f(v2.x);
        ay += es * bf2f(v2.y);
    }
    float inv = 1.f / fmaxf(s, 1e-12f);
    ushort2 o;
    o.x = f2bf(ax * inv); o.y = f2bf(ay * inv);
    *(ushort2*)(aggb + (size_t)node * DMODEL + hh * 32 + d2 * 2) = o;
}

// ---------------------------------------------------------------------------
// h = LN(h + add) * g + b ; also emit bf16 copy. One block (256 thr) per row.
__global__ __launch_bounds__(256) void add_ln_k(float* __restrict__ h,
                                                const float* __restrict__ add,
                                                const float* __restrict__ g,
                                                const float* __restrict__ b,
                                                unsigned short* __restrict__ hb) {
    const int r = blockIdx.x;
    const int t = threadIdx.x;
    float x = h[(size_t)r * DMODEL + t] + add[(size_t)r * DMODEL + t];
    __shared__ float red[4];
    float s = x;
    #pragma unroll
    for (int mk = 32; mk >= 1; mk >>= 1) s += __shfl_xor(s, mk);
    if ((t & 63) == 0) red[t >> 6] = s;
    __syncthreads();
    float mean = (red[0] + red[1] + red[2] + red[3]) * (1.f / DMODEL);
    float dx = x - mean;
    __syncthreads();
    float v = dx * dx;
    #pragma unroll
    for (int mk = 32; mk >= 1; mk >>= 1) v += __shfl_xor(v, mk);
    if ((t & 63) == 0) red[t >> 6] = v;
    __syncthreads();
    float var = (red[0] + red[1] + red[2] + red[3]) * (1.f / DMODEL);
    float y = dx * rsqrtf(var + 1e-5f) * g[t] + b[t];
    h[(size_t)r * DMODEL + t] = y;
    hb[(size_t)r * DMODEL + t] = f2bf(y);
}

// ---------------------------------------------------------------------------
extern "C" void kernel_launch(void* const* d_in, const int* in_sizes, int n_in,
                              void* d_out, int out_size, void* d_ws, size_t ws_size,
                              hipStream_t stream) {
    const float* x      = (const float*)d_in[0];
    const int*   row    = (const int*)d_in[1];
    const int*   col    = (const int*)d_in[2];
    const float* Wx     = (const float*)d_in[3];
    const float* bx     = (const float*)d_in[4];
    const float* degemb = (const float*)d_in[5];
    const float* sb     = (const float*)d_in[6];
    const float* Wq     = (const float*)d_in[7];
    const float* bq     = (const float*)d_in[8];
    const float* Wk     = (const float*)d_in[9];
    const float* bk     = (const float*)d_in[10];
    const float* Wv     = (const float*)d_in[11];
    const float* bv     = (const float*)d_in[12];
    const float* Wo     = (const float*)d_in[13];
    const float* bo     = (const float*)d_in[14];
    const float* ln1g   = (const float*)d_in[15];
    const float* ln1b   = (const float*)d_in[16];
    const float* ln2g   = (const float*)d_in[17];
    const float* ln2b   = (const float*)d_in[18];
    const float* W1     = (const float*)d_in[19];
    const float* b1     = (const float*)d_in[20];
    const float* W2     = (const float*)d_in[21];
    const float* b2     = (const float*)d_in[22];

    const int Nn = NNODES, E = NEDGES;
    float* h = (float*)d_out;

    // ---- workspace arena (bytes) ----
    char* w = (char*)d_ws;
    unsigned short* hb   = (unsigned short*)w; w += (size_t)Nn * DMODEL * 2;    // 10.24 MB
    unsigned short* QKVb = (unsigned short*)w; w += (size_t)Nn * 768 * 2;       // 30.72 MB
    unsigned short* AGGb = (unsigned short*)w; w += (size_t)Nn * DMODEL * 2;    // 10.24 MB
    unsigned short* FFb  = (unsigned short*)w; w += (size_t)Nn * DFF * 2;       // 20.48 MB
    float*          OUT  = (float*)w;          w += (size_t)Nn * DMODEL * 4;    // 20.48 MB
    unsigned short* xb   = (unsigned short*)w; w += (size_t)Nn * INC * 2;       //  5.12 MB
    unsigned short* Wxt  = (unsigned short*)w; w += (size_t)DMODEL * INC * 2;
    unsigned short* Wqkvt[NLAYER]; float* bqkv[NLAYER];
    unsigned short *Wot[NLAYER], *W1t[NLAYER], *W2t[NLAYER];
    for (int l = 0; l < NLAYER; ++l) {
        Wqkvt[l] = (unsigned short*)w; w += (size_t)768 * DMODEL * 2;
        bqkv[l]  = (float*)w;          w += 768 * 4;
        Wot[l]   = (unsigned short*)w; w += (size_t)DMODEL * DMODEL * 2;
        W1t[l]   = (unsigned short*)w; w += (size_t)DFF * DMODEL * 2;
        W2t[l]   = (unsigned short*)w; w += (size_t)DMODEL * DFF * 2;
    }
    int* CSR = (int*)w; w += (size_t)ETOT * 4;
    int* OFF = (int*)w; w += (Nn + 1) * 4;
    int* CUR = (int*)w; w += Nn * 4;
    int* DEG = (int*)w; w += Nn * 4;
    int* BKT = (int*)w; w += Nn * 4;

    // ---- graph preprocessing ----
    hipMemsetAsync(DEG, 0, Nn * sizeof(int), stream);
    count_deg_k<<<(E + 255) / 256, 256, 0, stream>>>(row, DEG, E);
    bucket_k<<<(Nn + 255) / 256, 256, 0, stream>>>(DEG, BKT, Nn);
    scan_offsets_k<<<1, 1024, 0, stream>>>(DEG, OFF, CUR, Nn);
    csr_fill_k<<<(E + Nn + 255) / 256, 256, 0, stream>>>(row, col, CUR, CSR, E, Nn);

    // ---- weight prep: fp32 [K][N] -> bf16 [N][K] ----
    cvt_bf16_k<<<((size_t)Nn * INC / 4 + 255) / 256, 256, 0, stream>>>(x, xb, Nn * INC);
    {
        dim3 g(DMODEL / 32, INC / 32);
        transpose_cvt_k<<<g, 256, 0, stream>>>(Wx, Wxt, INC, DMODEL);
    }
    for (int l = 0; l < NLAYER; ++l) {
        const size_t DD = (size_t)DMODEL * DMODEL;
        dim3 gDD(DMODEL / 32, DMODEL / 32);
        transpose_cvt_k<<<gDD, 256, 0, stream>>>(Wq + l * DD, Wqkvt[l],                DMODEL, DMODEL);
        transpose_cvt_k<<<gDD, 256, 0, stream>>>(Wk + l * DD, Wqkvt[l] + 256 * DMODEL, DMODEL, DMODEL);
        transpose_cvt_k<<<gDD, 256, 0, stream>>>(Wv + l * DD, Wqkvt[l] + 512 * DMODEL, DMODEL, DMODEL);
        concat3_k<<<3, 256, 0, stream>>>(bq + l * DMODEL, bk + l * DMODEL, bv + l * DMODEL, bqkv[l]);
        transpose_cvt_k<<<gDD, 256, 0, stream>>>(Wo + l * DD, Wot[l], DMODEL, DMODEL);
        dim3 g1(DFF / 32, DMODEL / 32);
        transpose_cvt_k<<<g1, 256, 0, stream>>>(W1 + (size_t)l * DMODEL * DFF, W1t[l], DMODEL, DFF);
        dim3 g2(DMODEL / 32, DFF / 32);
        transpose_cvt_k<<<g2, 256, 0, stream>>>(W2 + (size_t)l * DFF * DMODEL, W2t[l], DFF, DMODEL);
    }

    const int MB = (Nn + 127) / 128;  // 157

    // ---- embedding: h = x @ Wx + bx + deg_emb[bucket] ; also hb ----
    {
        dim3 grid(MB, DMODEL / 128);
        gemm_bf16_k<<<grid, 256, 0, stream>>>(xb, Wxt, bx, h, hb, Nn, INC, DMODEL,
                                              degemb, BKT, 0);
    }

    // ---- layers ----
    for (int l = 0; l < NLAYER; ++l) {
        const float* sb_i = sb + (size_t)l * NBUCKET * NHEAD;
        dim3 gQKV(MB, 768 / 128);
        dim3 gD(MB, DMODEL / 128);
        dim3 gF(MB, DFF / 128);

        gemm_bf16_k<<<gQKV, 256, 0, stream>>>(hb, Wqkvt[l], bqkv[l], nullptr, QKVb,
                                              Nn, DMODEL, 768, nullptr, nullptr, 0);
        attn_bf16_k<<<Nn, 128, 0, stream>>>(QKVb, OFF, CSR, BKT, sb_i, AGGb);
        gemm_bf16_k<<<gD, 256, 0, stream>>>(AGGb, Wot[l], bo + (size_t)l * DMODEL,
                                            OUT, nullptr, Nn, DMODEL, DMODEL,
                                            nullptr, nullptr, 0);
        add_ln_k<<<Nn, 256, 0, stream>>>(h, OUT, ln1g + (size_t)l * DMODEL,
                                         ln1b + (size_t)l * DMODEL, hb);
        gemm_bf16_k<<<gF, 256, 0, stream>>>(hb, W1t[l], b1 + (size_t)l * DFF,
                                            nullptr, FFb, Nn, DMODEL, DFF,
                                            nullptr, nullptr, 1);
        gemm_bf16_k<<<gD, 256, 0, stream>>>(FFb, W2t[l], b2 + (size_t)l * DMODEL,
                                            OUT, nullptr, Nn, DFF, DMODEL,
                                            nullptr, nullptr, 0);
        add_ln_k<<<Nn, 256, 0, stream>>>(h, OUT, ln2g + (size_t)l * DMODEL,
                                         ln2b + (size_t)l * DMODEL, hb);
    }
}

// Round 9
// 715.771 us; speedup vs baseline: 2.2843x; 1.1616x over previous
//
#include <hip/hip_runtime.h>
#include <hip/hip_bf16.h>
#include <math.h>

#define NNODES 20000
#define NEDGES 320000
#define INC 128
#define DMODEL 256
#define NHEAD 8
#define DHEAD 32
#define NLAYER 2
#define NBUCKET 64
#define DFF 512
#define ETOT (NEDGES + NNODES)
#define UNR 8

typedef __attribute__((ext_vector_type(8))) short short8v;
typedef __attribute__((ext_vector_type(4))) float f32x4;

__device__ __forceinline__ float bf2f(unsigned short u) {
    return __uint_as_float(((unsigned int)u) << 16);
}
__device__ __forceinline__ unsigned short f2bf(float f) {
    unsigned int u = __float_as_uint(f);
    unsigned int r = (u + 0x7FFFu + ((u >> 16) & 1u)) >> 16;
    return (unsigned short)r;
}

// ---------------------------------------------------------------------------
// Graph preprocessing
__global__ void count_deg_k(const int* __restrict__ row, int* __restrict__ deg, int E) {
    int e = blockIdx.x * 256 + threadIdx.x;
    if (e < E) atomicAdd(&deg[row[e]], 1);
}

__global__ void bucket_k(const int* __restrict__ deg, int* __restrict__ bkt, int n) {
    int i = blockIdx.x * 256 + threadIdx.x;
    if (i < n) {
        int d = deg[i]; if (d < 1) d = 1;
        int b = 31 - __clz(d);
        b = min(max(b, 1), NBUCKET - 1);
        bkt[i] = b;
    }
}

__global__ __launch_bounds__(1024) void scan_offsets_k(const int* __restrict__ deg,
                                                       int* __restrict__ off,
                                                       int* __restrict__ cur, int n) {
    const int T = 1024;
    int t = threadIdx.x;
    int chunk = (n + T - 1) / T;
    int base = t * chunk;
    int s = 0;
    for (int i = 0; i < chunk; ++i) {
        int idx = base + i;
        if (idx < n) s += deg[idx] + 1;
    }
    __shared__ int ps[1024];
    ps[t] = s;
    __syncthreads();
    for (int d = 1; d < T; d <<= 1) {
        int v = (t >= d) ? ps[t - d] : 0;
        __syncthreads();
        ps[t] += v;
        __syncthreads();
    }
    int run = (t == 0) ? 0 : ps[t - 1];
    for (int i = 0; i < chunk; ++i) {
        int idx = base + i;
        if (idx < n) {
            off[idx] = run; cur[idx] = run;
            run += deg[idx] + 1;
        }
    }
    if (t == T - 1) off[n] = ps[T - 1];
}

__global__ void csr_fill_k(const int* __restrict__ row, const int* __restrict__ col,
                           int* __restrict__ cur, int* __restrict__ csr, int E, int n) {
    int e = blockIdx.x * 256 + threadIdx.x;
    if (e < E) {
        int p = atomicAdd(&cur[row[e]], 1);
        csr[p] = col[e];
    } else if (e < E + n) {
        int nn = e - E;
        int p = atomicAdd(&cur[nn], 1);
        csr[p] = nn;
    }
}

// ---------------------------------------------------------------------------
// fp32 -> bf16 elementwise convert (4 elems/thread)
__global__ void cvt_bf16_k(const float* __restrict__ s, unsigned short* __restrict__ d, int n) {
    int i = (blockIdx.x * 256 + threadIdx.x) * 4;
    if (i < n) {
        float4 v = *(const float4*)(s + i);
        ushort4 o;
        o.x = f2bf(v.x); o.y = f2bf(v.y); o.z = f2bf(v.z); o.w = f2bf(v.w);
        *(ushort4*)(d + i) = o;
    }
}

// transpose + convert: src fp32 [K][N] -> dst bf16 [N][K]. K,N multiples of 32.
__global__ __launch_bounds__(256) void transpose_cvt_k(const float* __restrict__ src,
                                                       unsigned short* __restrict__ dst,
                                                       int K, int N) {
    __shared__ float tile[32][33];
    const int k0 = blockIdx.y * 32;
    const int n0 = blockIdx.x * 32;
    const int t = threadIdx.x;
    {
        int r = t >> 3, c = (t & 7) * 4;
        float4 v = *(const float4*)(src + (size_t)(k0 + r) * N + n0 + c);
        tile[r][c] = v.x; tile[r][c + 1] = v.y; tile[r][c + 2] = v.z; tile[r][c + 3] = v.w;
    }
    __syncthreads();
    {
        int n = t >> 3, k = (t & 7) * 4;
        ushort4 o;
        o.x = f2bf(tile[k][n]); o.y = f2bf(tile[k + 1][n]);
        o.z = f2bf(tile[k + 2][n]); o.w = f2bf(tile[k + 3][n]);
        *(ushort4*)(dst + (size_t)(n0 + n) * K + k0 + k) = o;
    }
}

__global__ void concat3_k(const float* a, const float* b, const float* c, float* d) {
    int t = blockIdx.x * 256 + threadIdx.x;
    if (t < 256) d[t] = a[t];
    else if (t < 512) d[t] = b[t - 256];
    else if (t < 768) d[t] = c[t - 512];
}

// ---------------------------------------------------------------------------
// bf16 MFMA GEMM: C[M,Nout] = A[M,K](bf16) @ Wt[Nout,K](bf16)^T + bias
//   optional: += emb[bkt[m]][n] ; optional gelu ; store fp32 (Cf) and/or bf16 (Cb)
// BM=BN=128, BK=32, 256 threads = 4 waves (2x2), wave tile 64x64 = 4x4 frags.
__global__ __launch_bounds__(256) void gemm_bf16_k(
        const unsigned short* __restrict__ A, const unsigned short* __restrict__ Wt,
        const float* __restrict__ bias,
        float* __restrict__ Cf, unsigned short* __restrict__ Cb,
        int M, int K, int Nout,
        const float* __restrict__ emb, const int* __restrict__ bkt, int act) {
    __shared__ unsigned short As[128 * 40];  // row stride 40 (pad 32->40): bank-spread
    __shared__ unsigned short Bs[128 * 40];
    const int bm = blockIdx.x * 128;
    const int bn = blockIdx.y * 128;
    const int t = threadIdx.x;
    const int wid = t >> 6, lane = t & 63;
    const int wm = wid >> 1, wn = wid & 1;
    const int l16 = lane & 15, kslc = lane >> 4;

    f32x4 acc[4][4] = {};

    const int mrow = t >> 1, half = t & 1;
    for (int k0 = 0; k0 < K; k0 += 32) {
        {
            const unsigned short* srcA = A + (size_t)(bm + mrow) * K + k0 + half * 16;
            uint4 v0 = {0, 0, 0, 0}, v1 = {0, 0, 0, 0};
            if (bm + mrow < M) {
                v0 = *(const uint4*)srcA;
                v1 = *(const uint4*)(srcA + 8);
            }
            *(uint4*)(&As[mrow * 40 + half * 16]) = v0;
            *(uint4*)(&As[mrow * 40 + half * 16 + 8]) = v1;
            const unsigned short* srcB = Wt + (size_t)(bn + mrow) * K + k0 + half * 16;
            *(uint4*)(&Bs[mrow * 40 + half * 16]) = *(const uint4*)srcB;
            *(uint4*)(&Bs[mrow * 40 + half * 16 + 8]) = *(const uint4*)(srcB + 8);
        }
        __syncthreads();
        short8v a[4], b[4];
        #pragma unroll
        for (int f = 0; f < 4; ++f) {
            a[f] = *(const short8v*)(&As[(wm * 64 + f * 16 + l16) * 40 + kslc * 8]);
            b[f] = *(const short8v*)(&Bs[(wn * 64 + f * 16 + l16) * 40 + kslc * 8]);
        }
        #pragma unroll
        for (int fm = 0; fm < 4; ++fm)
            #pragma unroll
            for (int fn = 0; fn < 4; ++fn)
                acc[fm][fn] = __builtin_amdgcn_mfma_f32_16x16x32_bf16(
                    a[fm], b[fn], acc[fm][fn], 0, 0, 0);
        __syncthreads();
    }

    // epilogue: C/D layout col=lane&15, row=(lane>>4)*4+reg
    #pragma unroll
    for (int fm = 0; fm < 4; ++fm) {
        #pragma unroll
        for (int fn = 0; fn < 4; ++fn) {
            int cc = wn * 64 + fn * 16 + l16;
            int gn = bn + cc;
            float bn_v = bias[gn];
            int rbase = bm + wm * 64 + fm * 16 + (lane >> 4) * 4;
            #pragma unroll
            for (int r = 0; r < 4; ++r) {
                int gm = rbase + r;
                if (gm >= M) continue;
                float v = acc[fm][fn][r] + bn_v;
                if (emb) v += emb[(size_t)bkt[gm] * Nout + gn];
                if (act) v = 0.5f * v * (1.f + erff(v * 0.70710678118654752f));
                if (Cf) Cf[(size_t)gm * Nout + gn] = v;
                if (Cb) Cb[(size_t)gm * Nout + gn] = f2bf(v);
            }
        }
    }
}

// ---------------------------------------------------------------------------
// Attention over CSR, bf16 QKV packed per node as [Q|K|V] (768 shorts).
// Block = 128 threads: head hh = t>>4 (8 heads), dim pair d2 = t&15.
// Single pass, online softmax, 8-edge batched gathers for MLP. No LDS.
__global__ __launch_bounds__(128) void attn_bf16_k(
        const unsigned short* __restrict__ QKV,
        const int* __restrict__ off, const int* __restrict__ csr,
        const int* __restrict__ bkt, const float* __restrict__ sb_i,
        unsigned short* __restrict__ aggb) {
    const int node = blockIdx.x;
    const int t = threadIdx.x;
    const int hh = t >> 4, d2 = t & 15;
    const int s0 = off[node], s1 = off[node + 1];
    const ushort2 q2 = *(const ushort2*)(QKV + (size_t)node * 768 + hh * 32 + d2 * 2);
    const float qx = bf2f(q2.x), qy = bf2f(q2.y);
    const float sbn = sb_i[bkt[node] * NHEAD + hh];
    const float scale = 0.17677669529663689f;  // 32^-0.5
    float m = -1e30f, s = 0.f, ax = 0.f, ay = 0.f;
    for (int j = s0; j < s1; j += UNR) {
        int cc[UNR];
        #pragma unroll
        for (int e = 0; e < UNR; ++e)
            cc[e] = csr[min(j + e, s1 - 1)];
        ushort2 kk[UNR], vv[UNR];
        #pragma unroll
        for (int e = 0; e < UNR; ++e) {
            const unsigned short* base = QKV + (size_t)cc[e] * 768 + hh * 32 + d2 * 2;
            kk[e] = *(const ushort2*)(base + 256);
            vv[e] = *(const ushort2*)(base + 512);
        }
        float sbc[UNR];
        #pragma unroll
        for (int e = 0; e < UNR; ++e)
            sbc[e] = sb_i[bkt[cc[e]] * NHEAD + hh];
        #pragma unroll
        for (int e = 0; e < UNR; ++e) {
            float p = qx * bf2f(kk[e].x) + qy * bf2f(kk[e].y);
            #pragma unroll
            for (int mk = 8; mk >= 1; mk >>= 1) p += __shfl_xor(p, mk);
            float sc = p * scale + sbn + sbc[e];
            if (j + e < s1) {   // uniform across block
                float mn = fmaxf(m, sc);
                float corr = __expf(m - mn);
                float es = __expf(sc - mn);
                s = s * corr + es;
                ax = ax * corr + es * bf2f(vv[e].x);
                ay = ay * corr + es * bf2f(vv[e].y);
                m = mn;
            }
        }
    }
    float inv = 1.f / fmaxf(s, 1e-12f);
    ushort2 o;
    o.x = f2bf(ax * inv); o.y = f2bf(ay * inv);
    *(ushort2*)(aggb + (size_t)node * DMODEL + hh * 32 + d2 * 2) = o;
}

// ---------------------------------------------------------------------------
// h = LN(h + add) * g + b ; also emit bf16 copy. One block (256 thr) per row.
__global__ __launch_bounds__(256) void add_ln_k(float* __restrict__ h,
                                                const float* __restrict__ add,
                                                const float* __restrict__ g,
                                                const float* __restrict__ b,
                                                unsigned short* __restrict__ hb) {
    const int r = blockIdx.x;
    const int t = threadIdx.x;
    float x = h[(size_t)r * DMODEL + t] + add[(size_t)r * DMODEL + t];
    __shared__ float red[4];
    float s = x;
    #pragma unroll
    for (int mk = 32; mk >= 1; mk >>= 1) s += __shfl_xor(s, mk);
    if ((t & 63) == 0) red[t >> 6] = s;
    __syncthreads();
    float mean = (red[0] + red[1] + red[2] + red[3]) * (1.f / DMODEL);
    float dx = x - mean;
    __syncthreads();
    float v = dx * dx;
    #pragma unroll
    for (int mk = 32; mk >= 1; mk >>= 1) v += __shfl_xor(v, mk);
    if ((t & 63) == 0) red[t >> 6] = v;
    __syncthreads();
    float var = (red[0] + red[1] + red[2] + red[3]) * (1.f / DMODEL);
    float y = dx * rsqrtf(var + 1e-5f) * g[t] + b[t];
    h[(size_t)r * DMODEL + t] = y;
    hb[(size_t)r * DMODEL + t] = f2bf(y);
}

// ---------------------------------------------------------------------------
extern "C" void kernel_launch(void* const* d_in, const int* in_sizes, int n_in,
                              void* d_out, int out_size, void* d_ws, size_t ws_size,
                              hipStream_t stream) {
    const float* x      = (const float*)d_in[0];
    const int*   row    = (const int*)d_in[1];
    const int*   col    = (const int*)d_in[2];
    const float* Wx     = (const float*)d_in[3];
    const float* bx     = (const float*)d_in[4];
    const float* degemb = (const float*)d_in[5];
    const float* sb     = (const float*)d_in[6];
    const float* Wq     = (const float*)d_in[7];
    const float* bq     = (const float*)d_in[8];
    const float* Wk     = (const float*)d_in[9];
    const float* bk     = (const float*)d_in[10];
    const float* Wv     = (const float*)d_in[11];
    const float* bv     = (const float*)d_in[12];
    const float* Wo     = (const float*)d_in[13];
    const float* bo     = (const float*)d_in[14];
    const float* ln1g   = (const float*)d_in[15];
    const float* ln1b   = (const float*)d_in[16];
    const float* ln2g   = (const float*)d_in[17];
    const float* ln2b   = (const float*)d_in[18];
    const float* W1     = (const float*)d_in[19];
    const float* b1     = (const float*)d_in[20];
    const float* W2     = (const float*)d_in[21];
    const float* b2     = (const float*)d_in[22];

    const int Nn = NNODES, E = NEDGES;
    float* h = (float*)d_out;

    // ---- workspace arena (bytes) ----
    char* w = (char*)d_ws;
    unsigned short* hb   = (unsigned short*)w; w += (size_t)Nn * DMODEL * 2;    // 10.24 MB
    unsigned short* QKVb = (unsigned short*)w; w += (size_t)Nn * 768 * 2;       // 30.72 MB
    unsigned short* AGGb = (unsigned short*)w; w += (size_t)Nn * DMODEL * 2;    // 10.24 MB
    unsigned short* FFb  = (unsigned short*)w; w += (size_t)Nn * DFF * 2;       // 20.48 MB
    float*          OUT  = (float*)w;          w += (size_t)Nn * DMODEL * 4;    // 20.48 MB
    unsigned short* xb   = (unsigned short*)w; w += (size_t)Nn * INC * 2;       //  5.12 MB
    unsigned short* Wxt  = (unsigned short*)w; w += (size_t)DMODEL * INC * 2;
    unsigned short* Wqkvt[NLAYER]; float* bqkv[NLAYER];
    unsigned short *Wot[NLAYER], *W1t[NLAYER], *W2t[NLAYER];
    for (int l = 0; l < NLAYER; ++l) {
        Wqkvt[l] = (unsigned short*)w; w += (size_t)768 * DMODEL * 2;
        bqkv[l]  = (float*)w;          w += 768 * 4;
        Wot[l]   = (unsigned short*)w; w += (size_t)DMODEL * DMODEL * 2;
        W1t[l]   = (unsigned short*)w; w += (size_t)DFF * DMODEL * 2;
        W2t[l]   = (unsigned short*)w; w += (size_t)DMODEL * DFF * 2;
    }
    int* CSR = (int*)w; w += (size_t)ETOT * 4;
    int* OFF = (int*)w; w += (Nn + 1) * 4;
    int* CUR = (int*)w; w += Nn * 4;
    int* DEG = (int*)w; w += Nn * 4;
    int* BKT = (int*)w; w += Nn * 4;

    // ---- graph preprocessing ----
    hipMemsetAsync(DEG, 0, Nn * sizeof(int), stream);
    count_deg_k<<<(E + 255) / 256, 256, 0, stream>>>(row, DEG, E);
    bucket_k<<<(Nn + 255) / 256, 256, 0, stream>>>(DEG, BKT, Nn);
    scan_offsets_k<<<1, 1024, 0, stream>>>(DEG, OFF, CUR, Nn);
    csr_fill_k<<<(E + Nn + 255) / 256, 256, 0, stream>>>(row, col, CUR, CSR, E, Nn);

    // ---- weight prep: fp32 [K][N] -> bf16 [N][K] ----
    cvt_bf16_k<<<((size_t)Nn * INC / 4 + 255) / 256, 256, 0, stream>>>(x, xb, Nn * INC);
    {
        dim3 g(DMODEL / 32, INC / 32);
        transpose_cvt_k<<<g, 256, 0, stream>>>(Wx, Wxt, INC, DMODEL);
    }
    for (int l = 0; l < NLAYER; ++l) {
        const size_t DD = (size_t)DMODEL * DMODEL;
        dim3 gDD(DMODEL / 32, DMODEL / 32);
        transpose_cvt_k<<<gDD, 256, 0, stream>>>(Wq + l * DD, Wqkvt[l],                DMODEL, DMODEL);
        transpose_cvt_k<<<gDD, 256, 0, stream>>>(Wk + l * DD, Wqkvt[l] + 256 * DMODEL, DMODEL, DMODEL);
        transpose_cvt_k<<<gDD, 256, 0, stream>>>(Wv + l * DD, Wqkvt[l] + 512 * DMODEL, DMODEL, DMODEL);
        concat3_k<<<3, 256, 0, stream>>>(bq + l * DMODEL, bk + l * DMODEL, bv + l * DMODEL, bqkv[l]);
        transpose_cvt_k<<<gDD, 256, 0, stream>>>(Wo + l * DD, Wot[l], DMODEL, DMODEL);
        dim3 g1(DFF / 32, DMODEL / 32);
        transpose_cvt_k<<<g1, 256, 0, stream>>>(W1 + (size_t)l * DMODEL * DFF, W1t[l], DMODEL, DFF);
        dim3 g2(DMODEL / 32, DFF / 32);
        transpose_cvt_k<<<g2, 256, 0, stream>>>(W2 + (size_t)l * DFF * DMODEL, W2t[l], DFF, DMODEL);
    }

    const int MB = (Nn + 127) / 128;  // 157

    // ---- embedding: h = x @ Wx + bx + deg_emb[bucket] ; also hb ----
    {
        dim3 grid(MB, DMODEL / 128);
        gemm_bf16_k<<<grid, 256, 0, stream>>>(xb, Wxt, bx, h, hb, Nn, INC, DMODEL,
                                              degemb, BKT, 0);
    }

    // ---- layers ----
    for (int l = 0; l < NLAYER; ++l) {
        const float* sb_i = sb + (size_t)l * NBUCKET * NHEAD;
        dim3 gQKV(MB, 768 / 128);
        dim3 gD(MB, DMODEL / 128);
        dim3 gF(MB, DFF / 128);

        gemm_bf16_k<<<gQKV, 256, 0, stream>>>(hb, Wqkvt[l], bqkv[l], nullptr, QKVb,
                                              Nn, DMODEL, 768, nullptr, nullptr, 0);
        attn_bf16_k<<<Nn, 128, 0, stream>>>(QKVb, OFF, CSR, BKT, sb_i, AGGb);
        gemm_bf16_k<<<gD, 256, 0, stream>>>(AGGb, Wot[l], bo + (size_t)l * DMODEL,
                                            OUT, nullptr, Nn, DMODEL, DMODEL,
                                            nullptr, nullptr, 0);
        add_ln_k<<<Nn, 256, 0, stream>>>(h, OUT, ln1g + (size_t)l * DMODEL,
                                         ln1b + (size_t)l * DMODEL, hb);
        gemm_bf16_k<<<gF, 256, 0, stream>>>(hb, W1t[l], b1 + (size_t)l * DFF,
                                            nullptr, FFb, Nn, DMODEL, DFF,
                                            nullptr, nullptr, 1);
        gemm_bf16_k<<<gD, 256, 0, stream>>>(FFb, W2t[l], b2 + (size_t)l * DMODEL,
                                            OUT, nullptr, Nn, DFF, DMODEL,
                                            nullptr, nullptr, 0);
        add_ln_k<<<Nn, 256, 0, stream>>>(h, OUT, ln2g + (size_t)l * DMODEL,
                                         ln2b + (size_t)l * DMODEL, hb);
    }
}

// Round 10
// 649.719 us; speedup vs baseline: 2.5165x; 1.1017x over previous
//
#include <hip/hip_runtime.h>
#include <hip/hip_bf16.h>
#include <math.h>

#define NNODES 20000
#define NEDGES 320000
#define INC 128
#define DMODEL 256
#define NHEAD 8
#define DHEAD 32
#define NLAYER 2
#define NBUCKET 64
#define DFF 512
#define ETOT (NEDGES + NNODES)
#define UNR 8

typedef __attribute__((ext_vector_type(8))) short short8v;
typedef __attribute__((ext_vector_type(4))) float f32x4;

__device__ __forceinline__ float bf2f(unsigned short u) {
    return __uint_as_float(((unsigned int)u) << 16);
}
__device__ __forceinline__ unsigned short f2bf(float f) {
    unsigned int u = __float_as_uint(f);
    unsigned int r = (u + 0x7FFFu + ((u >> 16) & 1u)) >> 16;
    return (unsigned short)r;
}

// ---------------------------------------------------------------------------
// Graph preprocessing
__global__ void count_deg_k(const int* __restrict__ row, int* __restrict__ deg, int E) {
    int e = blockIdx.x * 256 + threadIdx.x;
    if (e < E) atomicAdd(&deg[row[e]], 1);
}

__global__ void bucket_k(const int* __restrict__ deg, int* __restrict__ bkt, int n) {
    int i = blockIdx.x * 256 + threadIdx.x;
    if (i < n) {
        int d = deg[i]; if (d < 1) d = 1;
        int b = 31 - __clz(d);
        b = min(max(b, 1), NBUCKET - 1);
        bkt[i] = b;
    }
}

__global__ __launch_bounds__(1024) void scan_offsets_k(const int* __restrict__ deg,
                                                       int* __restrict__ off,
                                                       int* __restrict__ cur, int n) {
    const int T = 1024;
    int t = threadIdx.x;
    int chunk = (n + T - 1) / T;
    int base = t * chunk;
    int s = 0;
    for (int i = 0; i < chunk; ++i) {
        int idx = base + i;
        if (idx < n) s += deg[idx] + 1;
    }
    __shared__ int ps[1024];
    ps[t] = s;
    __syncthreads();
    for (int d = 1; d < T; d <<= 1) {
        int v = (t >= d) ? ps[t - d] : 0;
        __syncthreads();
        ps[t] += v;
        __syncthreads();
    }
    int run = (t == 0) ? 0 : ps[t - 1];
    for (int i = 0; i < chunk; ++i) {
        int idx = base + i;
        if (idx < n) {
            off[idx] = run; cur[idx] = run;
            run += deg[idx] + 1;
        }
    }
    if (t == T - 1) off[n] = ps[T - 1];
}

// fill CSR columns PACKED with the neighbor's degree bucket:
//   entry = col | (bkt[col] << 19)   (col < 2^19, bkt < 64)
__global__ void csr_fill_k(const int* __restrict__ row, const int* __restrict__ col,
                           const int* __restrict__ bkt,
                           int* __restrict__ cur, int* __restrict__ csr, int E, int n) {
    int e = blockIdx.x * 256 + threadIdx.x;
    if (e < E) {
        int c = col[e];
        int p = atomicAdd(&cur[row[e]], 1);
        csr[p] = c | (bkt[c] << 19);
    } else if (e < E + n) {
        int nn = e - E;
        int p = atomicAdd(&cur[nn], 1);
        csr[p] = nn | (bkt[nn] << 19);
    }
}

// ---------------------------------------------------------------------------
// fp32 -> bf16 elementwise convert (4 elems/thread)
__global__ void cvt_bf16_k(const float* __restrict__ s, unsigned short* __restrict__ d, int n) {
    int i = (blockIdx.x * 256 + threadIdx.x) * 4;
    if (i < n) {
        float4 v = *(const float4*)(s + i);
        ushort4 o;
        o.x = f2bf(v.x); o.y = f2bf(v.y); o.z = f2bf(v.z); o.w = f2bf(v.w);
        *(ushort4*)(d + i) = o;
    }
}

// transpose + convert: src fp32 [K][N] -> dst bf16 [N][K]. K,N multiples of 32.
__global__ __launch_bounds__(256) void transpose_cvt_k(const float* __restrict__ src,
                                                       unsigned short* __restrict__ dst,
                                                       int K, int N) {
    __shared__ float tile[32][33];
    const int k0 = blockIdx.y * 32;
    const int n0 = blockIdx.x * 32;
    const int t = threadIdx.x;
    {
        int r = t >> 3, c = (t & 7) * 4;
        float4 v = *(const float4*)(src + (size_t)(k0 + r) * N + n0 + c);
        tile[r][c] = v.x; tile[r][c + 1] = v.y; tile[r][c + 2] = v.z; tile[r][c + 3] = v.w;
    }
    __syncthreads();
    {
        int n = t >> 3, k = (t & 7) * 4;
        ushort4 o;
        o.x = f2bf(tile[k][n]); o.y = f2bf(tile[k + 1][n]);
        o.z = f2bf(tile[k + 2][n]); o.w = f2bf(tile[k + 3][n]);
        *(ushort4*)(dst + (size_t)(n0 + n) * K + k0 + k) = o;
    }
}

__global__ void concat3_k(const float* a, const float* b, const float* c, float* d) {
    int t = blockIdx.x * 256 + threadIdx.x;
    if (t < 256) d[t] = a[t];
    else if (t < 512) d[t] = b[t - 256];
    else if (t < 768) d[t] = c[t - 512];
}

// ---------------------------------------------------------------------------
// bf16 MFMA GEMM: C[M,Nout] = A[M,K](bf16) @ Wt[Nout,K](bf16)^T + bias
//   optional: += emb[bkt[m]][n] ; optional gelu ; store fp32 (Cf) and/or bf16 (Cb)
// BM=BN=128, BK=32, 256 threads = 4 waves (2x2), wave tile 64x64 = 4x4 frags.
__global__ __launch_bounds__(256) void gemm_bf16_k(
        const unsigned short* __restrict__ A, const unsigned short* __restrict__ Wt,
        const float* __restrict__ bias,
        float* __restrict__ Cf, unsigned short* __restrict__ Cb,
        int M, int K, int Nout,
        const float* __restrict__ emb, const int* __restrict__ bkt, int act) {
    __shared__ unsigned short As[128 * 40];  // row stride 40 (pad 32->40): bank-spread
    __shared__ unsigned short Bs[128 * 40];
    const int bm = blockIdx.x * 128;
    const int bn = blockIdx.y * 128;
    const int t = threadIdx.x;
    const int wid = t >> 6, lane = t & 63;
    const int wm = wid >> 1, wn = wid & 1;
    const int l16 = lane & 15, kslc = lane >> 4;

    f32x4 acc[4][4] = {};

    const int mrow = t >> 1, half = t & 1;
    for (int k0 = 0; k0 < K; k0 += 32) {
        {
            const unsigned short* srcA = A + (size_t)(bm + mrow) * K + k0 + half * 16;
            uint4 v0 = {0, 0, 0, 0}, v1 = {0, 0, 0, 0};
            if (bm + mrow < M) {
                v0 = *(const uint4*)srcA;
                v1 = *(const uint4*)(srcA + 8);
            }
            *(uint4*)(&As[mrow * 40 + half * 16]) = v0;
            *(uint4*)(&As[mrow * 40 + half * 16 + 8]) = v1;
            const unsigned short* srcB = Wt + (size_t)(bn + mrow) * K + k0 + half * 16;
            *(uint4*)(&Bs[mrow * 40 + half * 16]) = *(const uint4*)srcB;
            *(uint4*)(&Bs[mrow * 40 + half * 16 + 8]) = *(const uint4*)(srcB + 8);
        }
        __syncthreads();
        short8v a[4], b[4];
        #pragma unroll
        for (int f = 0; f < 4; ++f) {
            a[f] = *(const short8v*)(&As[(wm * 64 + f * 16 + l16) * 40 + kslc * 8]);
            b[f] = *(const short8v*)(&Bs[(wn * 64 + f * 16 + l16) * 40 + kslc * 8]);
        }
        #pragma unroll
        for (int fm = 0; fm < 4; ++fm)
            #pragma unroll
            for (int fn = 0; fn < 4; ++fn)
                acc[fm][fn] = __builtin_amdgcn_mfma_f32_16x16x32_bf16(
                    a[fm], b[fn], acc[fm][fn], 0, 0, 0);
        __syncthreads();
    }

    // epilogue: C/D layout col=lane&15, row=(lane>>4)*4+reg
    #pragma unroll
    for (int fm = 0; fm < 4; ++fm) {
        #pragma unroll
        for (int fn = 0; fn < 4; ++fn) {
            int cc = wn * 64 + fn * 16 + l16;
            int gn = bn + cc;
            float bn_v = bias[gn];
            int rbase = bm + wm * 64 + fm * 16 + (lane >> 4) * 4;
            #pragma unroll
            for (int r = 0; r < 4; ++r) {
                int gm = rbase + r;
                if (gm >= M) continue;
                float v = acc[fm][fn][r] + bn_v;
                if (emb) v += emb[(size_t)bkt[gm] * Nout + gn];
                if (act) v = 0.5f * v * (1.f + erff(v * 0.70710678118654752f));
                if (Cf) Cf[(size_t)gm * Nout + gn] = v;
                if (Cb) Cb[(size_t)gm * Nout + gn] = f2bf(v);
            }
        }
    }
}

// ---------------------------------------------------------------------------
// Attention over CSR (bucket-packed entries), bf16 QKV per node [Q|K|V].
// Block = 128 threads: head hh = t>>4, dim pair d2 = t&15.
// Online softmax; register-level software pipeline (ping-pong A/B batches).
// Math order identical to the unpipelined version (same absmax).

#define LOADB(CC, KK, VV, SB, J)                                               \
    do {                                                                        \
        _Pragma("unroll")                                                       \
        for (int e = 0; e < UNR; ++e)                                           \
            CC[e] = csr[min((J) + e, s1 - 1)];                                  \
        _Pragma("unroll")                                                       \
        for (int e = 0; e < UNR; ++e) {                                         \
            const unsigned short* base =                                        \
                QKV + (size_t)(CC[e] & 0x7FFFF) * 768 + hh * 32 + d2 * 2;       \
            KK[e] = *(const ushort2*)(base + 256);                              \
            VV[e] = *(const ushort2*)(base + 512);                              \
            SB[e] = sb_i[(CC[e] >> 19) * NHEAD + hh];                           \
        }                                                                       \
    } while (0)

#define COMPUTE(KK, VV, SB, J)                                                 \
    do {                                                                        \
        _Pragma("unroll")                                                       \
        for (int e = 0; e < UNR; ++e) {                                         \
            float p = qx * bf2f(KK[e].x) + qy * bf2f(KK[e].y);                  \
            _Pragma("unroll")                                                   \
            for (int mk = 8; mk >= 1; mk >>= 1) p += __shfl_xor(p, mk);         \
            float sc = p * scale + sbn + SB[e];                                 \
            if ((J) + e < s1) {                                                 \
                float mn = fmaxf(m, sc);                                        \
                float corr = __expf(m - mn);                                    \
                float es = __expf(sc - mn);                                     \
                s = s * corr + es;                                              \
                ax = ax * corr + es * bf2f(VV[e].x);                            \
                ay = ay * corr + es * bf2f(VV[e].y);                            \
                m = mn;                                                         \
            }                                                                   \
        }                                                                       \
    } while (0)

__global__ __launch_bounds__(128) void attn_bf16_k(
        const unsigned short* __restrict__ QKV,
        const int* __restrict__ off, const int* __restrict__ csr,
        const int* __restrict__ bkt, const float* __restrict__ sb_i,
        unsigned short* __restrict__ aggb) {
    const int node = blockIdx.x;
    const int t = threadIdx.x;
    const int hh = t >> 4, d2 = t & 15;
    const int s0 = off[node], s1 = off[node + 1];
    const ushort2 q2 = *(const ushort2*)(QKV + (size_t)node * 768 + hh * 32 + d2 * 2);
    const float qx = bf2f(q2.x), qy = bf2f(q2.y);
    const float sbn = sb_i[bkt[node] * NHEAD + hh];
    const float scale = 0.17677669529663689f;  // 32^-0.5
    float m = -1e30f, s = 0.f, ax = 0.f, ay = 0.f;

    int ccA[UNR]; ushort2 kkA[UNR], vvA[UNR]; float sbA[UNR];
    int ccB[UNR]; ushort2 kkB[UNR], vvB[UNR]; float sbB[UNR];

    LOADB(ccA, kkA, vvA, sbA, s0);
    for (int j = s0; j < s1; j += 2 * UNR) {
        LOADB(ccB, kkB, vvB, sbB, j + UNR);      // in flight during COMPUTE(A)
        COMPUTE(kkA, vvA, sbA, j);
        LOADB(ccA, kkA, vvA, sbA, j + 2 * UNR);  // in flight during COMPUTE(B)
        COMPUTE(kkB, vvB, sbB, j + UNR);
    }

    float inv = 1.f / fmaxf(s, 1e-12f);
    ushort2 o;
    o.x = f2bf(ax * inv); o.y = f2bf(ay * inv);
    *(ushort2*)(aggb + (size_t)node * DMODEL + hh * 32 + d2 * 2) = o;
}

// ---------------------------------------------------------------------------
// h = LN(h + add) * g + b ; also emit bf16 copy. One block (256 thr) per row.
__global__ __launch_bounds__(256) void add_ln_k(float* __restrict__ h,
                                                const float* __restrict__ add,
                                                const float* __restrict__ g,
                                                const float* __restrict__ b,
                                                unsigned short* __restrict__ hb) {
    const int r = blockIdx.x;
    const int t = threadIdx.x;
    float x = h[(size_t)r * DMODEL + t] + add[(size_t)r * DMODEL + t];
    __shared__ float red[4];
    float s = x;
    #pragma unroll
    for (int mk = 32; mk >= 1; mk >>= 1) s += __shfl_xor(s, mk);
    if ((t & 63) == 0) red[t >> 6] = s;
    __syncthreads();
    float mean = (red[0] + red[1] + red[2] + red[3]) * (1.f / DMODEL);
    float dx = x - mean;
    __syncthreads();
    float v = dx * dx;
    #pragma unroll
    for (int mk = 32; mk >= 1; mk >>= 1) v += __shfl_xor(v, mk);
    if ((t & 63) == 0) red[t >> 6] = v;
    __syncthreads();
    float var = (red[0] + red[1] + red[2] + red[3]) * (1.f / DMODEL);
    float y = dx * rsqrtf(var + 1e-5f) * g[t] + b[t];
    h[(size_t)r * DMODEL + t] = y;
    hb[(size_t)r * DMODEL + t] = f2bf(y);
}

// ---------------------------------------------------------------------------
extern "C" void kernel_launch(void* const* d_in, const int* in_sizes, int n_in,
                              void* d_out, int out_size, void* d_ws, size_t ws_size,
                              hipStream_t stream) {
    const float* x      = (const float*)d_in[0];
    const int*   row    = (const int*)d_in[1];
    const int*   col    = (const int*)d_in[2];
    const float* Wx     = (const float*)d_in[3];
    const float* bx     = (const float*)d_in[4];
    const float* degemb = (const float*)d_in[5];
    const float* sb     = (const float*)d_in[6];
    const float* Wq     = (const float*)d_in[7];
    const float* bq     = (const float*)d_in[8];
    const float* Wk     = (const float*)d_in[9];
    const float* bk     = (const float*)d_in[10];
    const float* Wv     = (const float*)d_in[11];
    const float* bv     = (const float*)d_in[12];
    const float* Wo     = (const float*)d_in[13];
    const float* bo     = (const float*)d_in[14];
    const float* ln1g   = (const float*)d_in[15];
    const float* ln1b   = (const float*)d_in[16];
    const float* ln2g   = (const float*)d_in[17];
    const float* ln2b   = (const float*)d_in[18];
    const float* W1     = (const float*)d_in[19];
    const float* b1     = (const float*)d_in[20];
    const float* W2     = (const float*)d_in[21];
    const float* b2     = (const float*)d_in[22];

    const int Nn = NNODES, E = NEDGES;
    float* h = (float*)d_out;

    // ---- workspace arena (bytes) ----
    char* w = (char*)d_ws;
    unsigned short* hb   = (unsigned short*)w; w += (size_t)Nn * DMODEL * 2;    // 10.24 MB
    unsigned short* QKVb = (unsigned short*)w; w += (size_t)Nn * 768 * 2;       // 30.72 MB
    unsigned short* AGGb = (unsigned short*)w; w += (size_t)Nn * DMODEL * 2;    // 10.24 MB
    unsigned short* FFb  = (unsigned short*)w; w += (size_t)Nn * DFF * 2;       // 20.48 MB
    float*          OUT  = (float*)w;          w += (size_t)Nn * DMODEL * 4;    // 20.48 MB
    unsigned short* xb   = (unsigned short*)w; w += (size_t)Nn * INC * 2;       //  5.12 MB
    unsigned short* Wxt  = (unsigned short*)w; w += (size_t)DMODEL * INC * 2;
    unsigned short* Wqkvt[NLAYER]; float* bqkv[NLAYER];
    unsigned short *Wot[NLAYER], *W1t[NLAYER], *W2t[NLAYER];
    for (int l = 0; l < NLAYER; ++l) {
        Wqkvt[l] = (unsigned short*)w; w += (size_t)768 * DMODEL * 2;
        bqkv[l]  = (float*)w;          w += 768 * 4;
        Wot[l]   = (unsigned short*)w; w += (size_t)DMODEL * DMODEL * 2;
        W1t[l]   = (unsigned short*)w; w += (size_t)DFF * DMODEL * 2;
        W2t[l]   = (unsigned short*)w; w += (size_t)DMODEL * DFF * 2;
    }
    int* CSR = (int*)w; w += (size_t)ETOT * 4;
    int* OFF = (int*)w; w += (Nn + 1) * 4;
    int* CUR = (int*)w; w += Nn * 4;
    int* DEG = (int*)w; w += Nn * 4;
    int* BKT = (int*)w; w += Nn * 4;

    // ---- graph preprocessing ----
    hipMemsetAsync(DEG, 0, Nn * sizeof(int), stream);
    count_deg_k<<<(E + 255) / 256, 256, 0, stream>>>(row, DEG, E);
    bucket_k<<<(Nn + 255) / 256, 256, 0, stream>>>(DEG, BKT, Nn);
    scan_offsets_k<<<1, 1024, 0, stream>>>(DEG, OFF, CUR, Nn);
    csr_fill_k<<<(E + Nn + 255) / 256, 256, 0, stream>>>(row, col, BKT, CUR, CSR, E, Nn);

    // ---- weight prep: fp32 [K][N] -> bf16 [N][K] ----
    cvt_bf16_k<<<((size_t)Nn * INC / 4 + 255) / 256, 256, 0, stream>>>(x, xb, Nn * INC);
    {
        dim3 g(DMODEL / 32, INC / 32);
        transpose_cvt_k<<<g, 256, 0, stream>>>(Wx, Wxt, INC, DMODEL);
    }
    for (int l = 0; l < NLAYER; ++l) {
        const size_t DD = (size_t)DMODEL * DMODEL;
        dim3 gDD(DMODEL / 32, DMODEL / 32);
        transpose_cvt_k<<<gDD, 256, 0, stream>>>(Wq + l * DD, Wqkvt[l],                DMODEL, DMODEL);
        transpose_cvt_k<<<gDD, 256, 0, stream>>>(Wk + l * DD, Wqkvt[l] + 256 * DMODEL, DMODEL, DMODEL);
        transpose_cvt_k<<<gDD, 256, 0, stream>>>(Wv + l * DD, Wqkvt[l] + 512 * DMODEL, DMODEL, DMODEL);
        concat3_k<<<3, 256, 0, stream>>>(bq + l * DMODEL, bk + l * DMODEL, bv + l * DMODEL, bqkv[l]);
        transpose_cvt_k<<<gDD, 256, 0, stream>>>(Wo + l * DD, Wot[l], DMODEL, DMODEL);
        dim3 g1(DFF / 32, DMODEL / 32);
        transpose_cvt_k<<<g1, 256, 0, stream>>>(W1 + (size_t)l * DMODEL * DFF, W1t[l], DMODEL, DFF);
        dim3 g2(DMODEL / 32, DFF / 32);
        transpose_cvt_k<<<g2, 256, 0, stream>>>(W2 + (size_t)l * DFF * DMODEL, W2t[l], DFF, DMODEL);
    }

    const int MB = (Nn + 127) / 128;  // 157

    // ---- embedding: h = x @ Wx + bx + deg_emb[bucket] ; also hb ----
    {
        dim3 grid(MB, DMODEL / 128);
        gemm_bf16_k<<<grid, 256, 0, stream>>>(xb, Wxt, bx, h, hb, Nn, INC, DMODEL,
                                              degemb, BKT, 0);
    }

    // ---- layers ----
    for (int l = 0; l < NLAYER; ++l) {
        const float* sb_i = sb + (size_t)l * NBUCKET * NHEAD;
        dim3 gQKV(MB, 768 / 128);
        dim3 gD(MB, DMODEL / 128);
        dim3 gF(MB, DFF / 128);

        gemm_bf16_k<<<gQKV, 256, 0, stream>>>(hb, Wqkvt[l], bqkv[l], nullptr, QKVb,
                                              Nn, DMODEL, 768, nullptr, nullptr, 0);
        attn_bf16_k<<<Nn, 128, 0, stream>>>(QKVb, OFF, CSR, BKT, sb_i, AGGb);
        gemm_bf16_k<<<gD, 256, 0, stream>>>(AGGb, Wot[l], bo + (size_t)l * DMODEL,
                                            OUT, nullptr, Nn, DMODEL, DMODEL,
                                            nullptr, nullptr, 0);
        add_ln_k<<<Nn, 256, 0, stream>>>(h, OUT, ln1g + (size_t)l * DMODEL,
                                         ln1b + (size_t)l * DMODEL, hb);
        gemm_bf16_k<<<gF, 256, 0, stream>>>(hb, W1t[l], b1 + (size_t)l * DFF,
                                            nullptr, FFb, Nn, DMODEL, DFF,
                                            nullptr, nullptr, 1);
        gemm_bf16_k<<<gD, 256, 0, stream>>>(FFb, W2t[l], b2 + (size_t)l * DMODEL,
                                            OUT, nullptr, Nn, DFF, DMODEL,
                                            nullptr, nullptr, 0);
        add_ln_k<<<Nn, 256, 0, stream>>>(h, OUT, ln2g + (size_t)l * DMODEL,
                                         ln2b + (size_t)l * DMODEL, hb);
    }
}

// Round 12
// 638.050 us; speedup vs baseline: 2.5626x; 1.0183x over previous
//
#include <hip/hip_runtime.h>
#include <hip/hip_bf16.h>
#include <math.h>

#define NNODES 20000
#define NPAD   20096   // 157*128: A-operand row padding for global_load_lds safety
#define NEDGES 320000
#define INC 128
#define DMODEL 256
#define NHEAD 8
#define DHEAD 32
#define NLAYER 2
#define NBUCKET 64
#define DFF 512
#define ETOT (NEDGES + NNODES)
#define UNR 8

typedef __attribute__((ext_vector_type(8))) short short8v;
typedef __attribute__((ext_vector_type(4))) float f32x4;

__device__ __forceinline__ float bf2f(unsigned short u) {
    return __uint_as_float(((unsigned int)u) << 16);
}
__device__ __forceinline__ unsigned short f2bf(float f) {
    unsigned int u = __float_as_uint(f);
    unsigned int r = (u + 0x7FFFu + ((u >> 16) & 1u)) >> 16;
    return (unsigned short)r;
}
// async global->LDS, 16B per lane; LDS dest = wave-uniform base + lane*16
__device__ __forceinline__ void gl16(const unsigned short* g, unsigned short* l) {
    __builtin_amdgcn_global_load_lds(
        (const __attribute__((address_space(1))) void*)g,
        (__attribute__((address_space(3))) void*)l, 16, 0, 0);
}

// ---------------------------------------------------------------------------
// Graph preprocessing
__global__ void count_deg_k(const int* __restrict__ row, int* __restrict__ deg, int E) {
    int e = blockIdx.x * 256 + threadIdx.x;
    if (e < E) atomicAdd(&deg[row[e]], 1);
}

// exclusive scan of (deg+1) -> off, cur; also bucket = clip(floor(log2(max(deg,1))),1,63)
__global__ __launch_bounds__(1024) void scan_offsets_k(const int* __restrict__ deg,
                                                       int* __restrict__ off,
                                                       int* __restrict__ cur,
                                                       int* __restrict__ bkt, int n) {
    const int T = 1024;
    int t = threadIdx.x;
    int chunk = (n + T - 1) / T;
    int base = t * chunk;
    int s = 0;
    for (int i = 0; i < chunk; ++i) {
        int idx = base + i;
        if (idx < n) {
            int d = deg[idx];
            int dd = d < 1 ? 1 : d;
            int b = 31 - __clz(dd);
            bkt[idx] = min(max(b, 1), NBUCKET - 1);
            s += d + 1;
        }
    }
    __shared__ int ps[1024];
    ps[t] = s;
    __syncthreads();
    for (int d = 1; d < T; d <<= 1) {
        int v = (t >= d) ? ps[t - d] : 0;
        __syncthreads();
        ps[t] += v;
        __syncthreads();
    }
    int run = (t == 0) ? 0 : ps[t - 1];
    for (int i = 0; i < chunk; ++i) {
        int idx = base + i;
        if (idx < n) {
            off[idx] = run; cur[idx] = run;
            run += deg[idx] + 1;
        }
    }
    if (t == T - 1) off[n] = ps[T - 1];
}

// fill CSR columns PACKED with the neighbor's degree bucket: col | bkt[col]<<19
__global__ void csr_fill_k(const int* __restrict__ row, const int* __restrict__ col,
                           const int* __restrict__ bkt,
                           int* __restrict__ cur, int* __restrict__ csr, int E, int n) {
    int e = blockIdx.x * 256 + threadIdx.x;
    if (e < E) {
        int c = col[e];
        int p = atomicAdd(&cur[row[e]], 1);
        csr[p] = c | (bkt[c] << 19);
    } else if (e < E + n) {
        int nn = e - E;
        int p = atomicAdd(&cur[nn], 1);
        csr[p] = nn | (bkt[nn] << 19);
    }
}

// ---------------------------------------------------------------------------
// fp32 -> bf16 elementwise convert (4 elems/thread)
__global__ void cvt_bf16_k(const float* __restrict__ s, unsigned short* __restrict__ d, int n) {
    int i = (blockIdx.x * 256 + threadIdx.x) * 4;
    if (i < n) {
        float4 v = *(const float4*)(s + i);
        ushort4 o;
        o.x = f2bf(v.x); o.y = f2bf(v.y); o.z = f2bf(v.z); o.w = f2bf(v.w);
        *(ushort4*)(d + i) = o;
    }
}

// ---------------------------------------------------------------------------
// ALL weight transposes (fp32 [K][N] -> bf16 [N][K]) in ONE kernel.
struct TDesc { const float* src; unsigned short* dst; int K; int N; int tileStart; };
struct TPack { TDesc d[13]; int nd; };

__global__ __launch_bounds__(256) void mega_transpose_k(TPack p) {
    __shared__ float tile[32][33];
    const int tb = blockIdx.x;
    int di = 0;
    for (int i = 1; i < 13; ++i)
        if (i < p.nd && p.d[i].tileStart <= tb) di = i;
    const float* __restrict__ src = p.d[di].src;
    unsigned short* __restrict__ dst = p.d[di].dst;
    const int K = p.d[di].K, N = p.d[di].N;
    const int local = tb - p.d[di].tileStart;
    const int tpn = N >> 5;
    const int n0 = (local % tpn) * 32;
    const int k0 = (local / tpn) * 32;
    const int t = threadIdx.x;
    {
        int r = t >> 3, c = (t & 7) * 4;
        float4 v = *(const float4*)(src + (size_t)(k0 + r) * N + n0 + c);
        tile[r][c] = v.x; tile[r][c + 1] = v.y; tile[r][c + 2] = v.z; tile[r][c + 3] = v.w;
    }
    __syncthreads();
    {
        int n = t >> 3, k = (t & 7) * 4;
        ushort4 o;
        o.x = f2bf(tile[k][n]); o.y = f2bf(tile[k + 1][n]);
        o.z = f2bf(tile[k + 2][n]); o.w = f2bf(tile[k + 3][n]);
        *(ushort4*)(dst + (size_t)(n0 + n) * K + k0 + k) = o;
    }
}

// both layers' q|k|v bias concat in one kernel: grid 6 x 256
__global__ void concat_bias2_k(const float* __restrict__ bq, const float* __restrict__ bk,
                               const float* __restrict__ bv,
                               float* __restrict__ d0, float* __restrict__ d1) {
    int t = blockIdx.x * 256 + threadIdx.x;      // 0..1535
    int l = t / 768, u = t - l * 768;
    float v;
    if (u < 256) v = bq[l * DMODEL + u];
    else if (u < 512) v = bk[l * DMODEL + u - 256];
    else v = bv[l * DMODEL + u - 512];
    (l ? d1 : d0)[u] = v;
}

// ---------------------------------------------------------------------------
// bf16 MFMA GEMM: C[M,Nout] = A[M,K](bf16) @ Wt[Nout,K](bf16)^T + bias
// BM=BN=128, BK=32, 256 threads = 4 waves (2x2), wave tile 64x64 = 4x4 frags.
// Staging via global_load_lds width=16 into LINEAR LDS (m97 pattern).
// A must have >= ceil(M/128)*128 allocated rows (NPAD) — garbage rows only feed
// D rows >= M which are guarded at store (16x16x32 D-row r depends only on A-row r).
__global__ __launch_bounds__(256) void gemm_bf16_k(
        const unsigned short* __restrict__ A, const unsigned short* __restrict__ Wt,
        const float* __restrict__ bias,
        float* __restrict__ Cf, unsigned short* __restrict__ Cb,
        int M, int K, int Nout,
        const float* __restrict__ emb, const int* __restrict__ bkt, int act) {
    __shared__ unsigned short As[128 * 32];  // linear [row][32k], 64 B/row
    __shared__ unsigned short Bs[128 * 32];
    const int bm = blockIdx.x * 128;
    const int bn = blockIdx.y * 128;
    const int t = threadIdx.x;
    const int wid = t >> 6, lane = t & 63;
    const int wm = wid >> 1, wn = wid & 1;
    const int l16 = lane & 15, kslc = lane >> 4;
    // staging: wave wid covers rows [wid*32, wid*32+32); lane -> (row = +lane/4, col=(lane&3)*8)
    const int srow = lane >> 2, scol = (lane & 3) * 8;

    f32x4 acc[4][4] = {};

    for (int k0 = 0; k0 < K; k0 += 32) {
        const unsigned short* gA = A + (size_t)(bm + wid * 32 + srow) * K + k0 + scol;
        const unsigned short* gB = Wt + (size_t)(bn + wid * 32 + srow) * K + k0 + scol;
        gl16(gA,          &As[(wid * 32) * 32]);
        gl16(gA + 16 * K, &As[(wid * 32 + 16) * 32]);
        gl16(gB,          &Bs[(wid * 32) * 32]);
        gl16(gB + 16 * K, &Bs[(wid * 32 + 16) * 32]);
        __syncthreads();
        short8v a[4], b[4];
        #pragma unroll
        for (int f = 0; f < 4; ++f) {
            a[f] = *(const short8v*)(&As[(wm * 64 + f * 16 + l16) * 32 + kslc * 8]);
            b[f] = *(const short8v*)(&Bs[(wn * 64 + f * 16 + l16) * 32 + kslc * 8]);
        }
        #pragma unroll
        for (int fm = 0; fm < 4; ++fm)
            #pragma unroll
            for (int fn = 0; fn < 4; ++fn)
                acc[fm][fn] = __builtin_amdgcn_mfma_f32_16x16x32_bf16(
                    a[fm], b[fn], acc[fm][fn], 0, 0, 0);
        __syncthreads();
    }

    // epilogue: C/D layout col=lane&15, row=(lane>>4)*4+reg
    #pragma unroll
    for (int fm = 0; fm < 4; ++fm) {
        #pragma unroll
        for (int fn = 0; fn < 4; ++fn) {
            int cc = wn * 64 + fn * 16 + l16;
            int gn = bn + cc;
            float bn_v = bias[gn];
            int rbase = bm + wm * 64 + fm * 16 + (lane >> 4) * 4;
            #pragma unroll
            for (int r = 0; r < 4; ++r) {
                int gm = rbase + r;
                if (gm >= M) continue;
                float v = acc[fm][fn][r] + bn_v;
                if (emb) v += emb[(size_t)bkt[gm] * Nout + gn];
                if (act) v = 0.5f * v * (1.f + erff(v * 0.70710678118654752f));
                if (Cf) Cf[(size_t)gm * Nout + gn] = v;
                if (Cb) Cb[(size_t)gm * Nout + gn] = f2bf(v);
            }
        }
    }
}

// ---------------------------------------------------------------------------
// Attention over CSR (bucket-packed entries), bf16 QKV per node [Q|K|V].
// Block = 128 threads: head hh = t>>4, dim pair d2 = t&15.
// Online softmax; register-level software pipeline (ping-pong A/B batches).

#define LOADB(CC, KK, VV, SB, J)                                               \
    do {                                                                        \
        _Pragma("unroll")                                                       \
        for (int e = 0; e < UNR; ++e)                                           \
            CC[e] = csr[min((J) + e, s1 - 1)];                                  \
        _Pragma("unroll")                                                       \
        for (int e = 0; e < UNR; ++e) {                                         \
            const unsigned short* base =                                        \
                QKV + (size_t)(CC[e] & 0x7FFFF) * 768 + hh * 32 + d2 * 2;       \
            KK[e] = *(const ushort2*)(base + 256);                              \
            VV[e] = *(const ushort2*)(base + 512);                              \
            SB[e] = sb_i[(CC[e] >> 19) * NHEAD + hh];                           \
        }                                                                       \
    } while (0)

#define COMPUTE(KK, VV, SB, J)                                                 \
    do {                                                                        \
        _Pragma("unroll")                                                       \
        for (int e = 0; e < UNR; ++e) {                                         \
            float p = qx * bf2f(KK[e].x) + qy * bf2f(KK[e].y);                  \
            _Pragma("unroll")                                                   \
            for (int mk = 8; mk >= 1; mk >>= 1) p += __shfl_xor(p, mk);         \
            float sc = p * scale + sbn + SB[e];                                 \
            if ((J) + e < s1) {                                                 \
                float mn = fmaxf(m, sc);                                        \
                float corr = __expf(m - mn);                                    \
                float es = __expf(sc - mn);                                     \
                s = s * corr + es;                                              \
                ax = ax * corr + es * bf2f(VV[e].x);                            \
                ay = ay * corr + es * bf2f(VV[e].y);                            \
                m = mn;                                                         \
            }                                                                   \
        }                                                                       \
    } while (0)

__global__ __launch_bounds__(128) void attn_bf16_k(
        const unsigned short* __restrict__ QKV,
        const int* __restrict__ off, const int* __restrict__ csr,
        const int* __restrict__ bkt, const float* __restrict__ sb_i,
        unsigned short* __restrict__ aggb) {
    const int node = blockIdx.x;
    const int t = threadIdx.x;
    const int hh = t >> 4, d2 = t & 15;
    const int s0 = off[node], s1 = off[node + 1];
    const ushort2 q2 = *(const ushort2*)(QKV + (size_t)node * 768 + hh * 32 + d2 * 2);
    const float qx = bf2f(q2.x), qy = bf2f(q2.y);
    const float sbn = sb_i[bkt[node] * NHEAD + hh];
    const float scale = 0.17677669529663689f;  // 32^-0.5
    float m = -1e30f, s = 0.f, ax = 0.f, ay = 0.f;

    int ccA[UNR]; ushort2 kkA[UNR], vvA[UNR]; float sbA[UNR];
    int ccB[UNR]; ushort2 kkB[UNR], vvB[UNR]; float sbB[UNR];

    LOADB(ccA, kkA, vvA, sbA, s0);
    for (int j = s0; j < s1; j += 2 * UNR) {
        LOADB(ccB, kkB, vvB, sbB, j + UNR);
        COMPUTE(kkA, vvA, sbA, j);
        LOADB(ccA, kkA, vvA, sbA, j + 2 * UNR);
        COMPUTE(kkB, vvB, sbB, j + UNR);
    }

    float inv = 1.f / fmaxf(s, 1e-12f);
    ushort2 o;
    o.x = f2bf(ax * inv); o.y = f2bf(ay * inv);
    *(ushort2*)(aggb + (size_t)node * DMODEL + hh * 32 + d2 * 2) = o;
}

// ---------------------------------------------------------------------------
// h = LN(h + add) * g + b ; also emit bf16 copy. One block (256 thr) per row.
__global__ __launch_bounds__(256) void add_ln_k(float* __restrict__ h,
                                                const float* __restrict__ add,
                                                const float* __restrict__ g,
                                                const float* __restrict__ b,
                                                unsigned short* __restrict__ hb) {
    const int r = blockIdx.x;
    const int t = threadIdx.x;
    float x = h[(size_t)r * DMODEL + t] + add[(size_t)r * DMODEL + t];
    __shared__ float red[4];
    float s = x;
    #pragma unroll
    for (int mk = 32; mk >= 1; mk >>= 1) s += __shfl_xor(s, mk);
    if ((t & 63) == 0) red[t >> 6] = s;
    __syncthreads();
    float mean = (red[0] + red[1] + red[2] + red[3]) * (1.f / DMODEL);
    float dx = x - mean;
    __syncthreads();
    float v = dx * dx;
    #pragma unroll
    for (int mk = 32; mk >= 1; mk >>= 1) v += __shfl_xor(v, mk);
    if ((t & 63) == 0) red[t >> 6] = v;
    __syncthreads();
    float var = (red[0] + red[1] + red[2] + red[3]) * (1.f / DMODEL);
    float y = dx * rsqrtf(var + 1e-5f) * g[t] + b[t];
    h[(size_t)r * DMODEL + t] = y;
    hb[(size_t)r * DMODEL + t] = f2bf(y);
}

// ---------------------------------------------------------------------------
extern "C" void kernel_launch(void* const* d_in, const int* in_sizes, int n_in,
                              void* d_out, int out_size, void* d_ws, size_t ws_size,
                              hipStream_t stream) {
    const float* x      = (const float*)d_in[0];
    const int*   row    = (const int*)d_in[1];
    const int*   col    = (const int*)d_in[2];
    const float* Wx     = (const float*)d_in[3];
    const float* bx     = (const float*)d_in[4];
    const float* degemb = (const float*)d_in[5];
    const float* sb     = (const float*)d_in[6];
    const float* Wq     = (const float*)d_in[7];
    const float* bq     = (const float*)d_in[8];
    const float* Wk     = (const float*)d_in[9];
    const float* bk     = (const float*)d_in[10];
    const float* Wv     = (const float*)d_in[11];
    const float* bv     = (const float*)d_in[12];
    const float* Wo     = (const float*)d_in[13];
    const float* bo     = (const float*)d_in[14];
    const float* ln1g   = (const float*)d_in[15];
    const float* ln1b   = (const float*)d_in[16];
    const float* ln2g   = (const float*)d_in[17];
    const float* ln2b   = (const float*)d_in[18];
    const float* W1     = (const float*)d_in[19];
    const float* b1     = (const float*)d_in[20];
    const float* W2     = (const float*)d_in[21];
    const float* b2     = (const float*)d_in[22];

    const int Nn = NNODES, E = NEDGES;
    float* h = (float*)d_out;

    // ---- workspace arena (bytes). A-operand matrices padded to NPAD rows. ----
    char* w = (char*)d_ws;
    unsigned short* hb   = (unsigned short*)w; w += (size_t)NPAD * DMODEL * 2;
    unsigned short* QKVb = (unsigned short*)w; w += (size_t)Nn * 768 * 2;
    unsigned short* AGGb = (unsigned short*)w; w += (size_t)NPAD * DMODEL * 2;
    unsigned short* FFb  = (unsigned short*)w; w += (size_t)NPAD * DFF * 2;
    float*          OUT  = (float*)w;          w += (size_t)Nn * DMODEL * 4;
    unsigned short* xb   = (unsigned short*)w; w += (size_t)NPAD * INC * 2;
    unsigned short* Wxt  = (unsigned short*)w; w += (size_t)DMODEL * INC * 2;
    unsigned short* Wqkvt[NLAYER]; float* bqkv[NLAYER];
    unsigned short *Wot[NLAYER], *W1t[NLAYER], *W2t[NLAYER];
    for (int l = 0; l < NLAYER; ++l) {
        Wqkvt[l] = (unsigned short*)w; w += (size_t)768 * DMODEL * 2;
        bqkv[l]  = (float*)w;          w += 768 * 4;
        Wot[l]   = (unsigned short*)w; w += (size_t)DMODEL * DMODEL * 2;
        W1t[l]   = (unsigned short*)w; w += (size_t)DFF * DMODEL * 2;
        W2t[l]   = (unsigned short*)w; w += (size_t)DMODEL * DFF * 2;
    }
    int* CSR = (int*)w; w += (size_t)ETOT * 4;
    int* OFF = (int*)w; w += (Nn + 1) * 4;
    int* CUR = (int*)w; w += Nn * 4;
    int* DEG = (int*)w; w += Nn * 4;
    int* BKT = (int*)w; w += Nn * 4;

    // ---- graph preprocessing ----
    hipMemsetAsync(DEG, 0, Nn * sizeof(int), stream);
    count_deg_k<<<(E + 255) / 256, 256, 0, stream>>>(row, DEG, E);
    scan_offsets_k<<<1, 1024, 0, stream>>>(DEG, OFF, CUR, BKT, Nn);
    csr_fill_k<<<(E + Nn + 255) / 256, 256, 0, stream>>>(row, col, BKT, CUR, CSR, E, Nn);

    // ---- input convert + ALL weight transposes (1 kernel) + bias concat (1 kernel) ----
    cvt_bf16_k<<<((size_t)Nn * INC / 4 + 255) / 256, 256, 0, stream>>>(x, xb, Nn * INC);
    {
        TPack pk; int nd = 0, tt = 0;
        auto add = [&](const float* s, unsigned short* d, int K, int N) {
            pk.d[nd].src = s; pk.d[nd].dst = d; pk.d[nd].K = K; pk.d[nd].N = N;
            pk.d[nd].tileStart = tt;
            tt += (K / 32) * (N / 32);
            ++nd;
        };
        const size_t DD = (size_t)DMODEL * DMODEL;
        add(Wx, Wxt, INC, DMODEL);
        for (int l = 0; l < NLAYER; ++l) {
            add(Wq + l * DD, Wqkvt[l],                DMODEL, DMODEL);
            add(Wk + l * DD, Wqkvt[l] + 256 * DMODEL, DMODEL, DMODEL);
            add(Wv + l * DD, Wqkvt[l] + 512 * DMODEL, DMODEL, DMODEL);
            add(Wo + l * DD, Wot[l], DMODEL, DMODEL);
            add(W1 + (size_t)l * DMODEL * DFF, W1t[l], DMODEL, DFF);
            add(W2 + (size_t)l * DFF * DMODEL, W2t[l], DFF, DMODEL);
        }
        pk.nd = nd;  // 13
        mega_transpose_k<<<tt, 256, 0, stream>>>(pk);  // tt = 1056
        concat_bias2_k<<<6, 256, 0, stream>>>(bq, bk, bv, bqkv[0], bqkv[1]);
    }

    const int MB = (Nn + 127) / 128;  // 157

    // ---- embedding: h = x @ Wx + bx + deg_emb[bucket] ; also hb ----
    {
        dim3 grid(MB, DMODEL / 128);
        gemm_bf16_k<<<grid, 256, 0, stream>>>(xb, Wxt, bx, h, hb, Nn, INC, DMODEL,
                                              degemb, BKT, 0);
    }

    // ---- layers ----
    for (int l = 0; l < NLAYER; ++l) {
        const float* sb_i = sb + (size_t)l * NBUCKET * NHEAD;
        dim3 gQKV(MB, 768 / 128);
        dim3 gD(MB, DMODEL / 128);
        dim3 gF(MB, DFF / 128);

        gemm_bf16_k<<<gQKV, 256, 0, stream>>>(hb, Wqkvt[l], bqkv[l], nullptr, QKVb,
                                              Nn, DMODEL, 768, nullptr, nullptr, 0);
        attn_bf16_k<<<Nn, 128, 0, stream>>>(QKVb, OFF, CSR, BKT, sb_i, AGGb);
        gemm_bf16_k<<<gD, 256, 0, stream>>>(AGGb, Wot[l], bo + (size_t)l * DMODEL,
                                            OUT, nullptr, Nn, DMODEL, DMODEL,
                                            nullptr, nullptr, 0);
        add_ln_k<<<Nn, 256, 0, stream>>>(h, OUT, ln1g + (size_t)l * DMODEL,
                                         ln1b + (size_t)l * DMODEL, hb);
        gemm_bf16_k<<<gF, 256, 0, stream>>>(hb, W1t[l], b1 + (size_t)l * DFF,
                                            nullptr, FFb, Nn, DMODEL, DFF,
                                            nullptr, nullptr, 1);
        gemm_bf16_k<<<gD, 256, 0, stream>>>(FFb, W2t[l], b2 + (size_t)l * DMODEL,
                                            OUT, nullptr, Nn, DFF, DMODEL,
                                            nullptr, nullptr, 0);
        add_ln_k<<<Nn, 256, 0, stream>>>(h, OUT, ln2g + (size_t)l * DMODEL,
                                         ln2b + (size_t)l * DMODEL, hb);
    }
}

// Round 13
// 632.759 us; speedup vs baseline: 2.5840x; 1.0084x over previous
//
#include <hip/hip_runtime.h>
#include <hip/hip_bf16.h>
#include <math.h>

#define NNODES 20000
#define NPAD   20096   // 157*128: A-operand row padding for global_load_lds safety
#define NEDGES 320000
#define INC 128
#define DMODEL 256
#define NHEAD 8
#define DHEAD 32
#define NLAYER 2
#define NBUCKET 64
#define DFF 512
#define ETOT (NEDGES + NNODES)
#define UNR 8

typedef __attribute__((ext_vector_type(8))) short short8v;
typedef __attribute__((ext_vector_type(4))) float f32x4;

__device__ __forceinline__ float bf2f(unsigned short u) {
    return __uint_as_float(((unsigned int)u) << 16);
}
__device__ __forceinline__ unsigned short f2bf(float f) {
    unsigned int u = __float_as_uint(f);
    unsigned int r = (u + 0x7FFFu + ((u >> 16) & 1u)) >> 16;
    return (unsigned short)r;
}
// async global->LDS, 16B per lane; LDS dest = wave-uniform base + lane*16
__device__ __forceinline__ void gl16(const unsigned short* g, unsigned short* l) {
    __builtin_amdgcn_global_load_lds(
        (const __attribute__((address_space(1))) void*)g,
        (__attribute__((address_space(3))) void*)l, 16, 0, 0);
}

// ---------------------------------------------------------------------------
// Graph preprocessing
__global__ void count_deg_k(const int* __restrict__ row, int* __restrict__ deg, int E) {
    int e = blockIdx.x * 256 + threadIdx.x;
    if (e < E) atomicAdd(&deg[row[e]], 1);
}

// exclusive scan of (deg+1) -> off, cur; also bucket = clip(floor(log2(max(deg,1))),1,63)
__global__ __launch_bounds__(1024) void scan_offsets_k(const int* __restrict__ deg,
                                                       int* __restrict__ off,
                                                       int* __restrict__ cur,
                                                       int* __restrict__ bkt, int n) {
    const int T = 1024;
    int t = threadIdx.x;
    int chunk = (n + T - 1) / T;
    int base = t * chunk;
    int s = 0;
    for (int i = 0; i < chunk; ++i) {
        int idx = base + i;
        if (idx < n) {
            int d = deg[idx];
            int dd = d < 1 ? 1 : d;
            int b = 31 - __clz(dd);
            bkt[idx] = min(max(b, 1), NBUCKET - 1);
            s += d + 1;
        }
    }
    __shared__ int ps[1024];
    ps[t] = s;
    __syncthreads();
    for (int d = 1; d < T; d <<= 1) {
        int v = (t >= d) ? ps[t - d] : 0;
        __syncthreads();
        ps[t] += v;
        __syncthreads();
    }
    int run = (t == 0) ? 0 : ps[t - 1];
    for (int i = 0; i < chunk; ++i) {
        int idx = base + i;
        if (idx < n) {
            off[idx] = run; cur[idx] = run;
            run += deg[idx] + 1;
        }
    }
    if (t == T - 1) off[n] = ps[T - 1];
}

// fill CSR columns PACKED with the neighbor's degree bucket: col | bkt[col]<<19
__global__ void csr_fill_k(const int* __restrict__ row, const int* __restrict__ col,
                           const int* __restrict__ bkt,
                           int* __restrict__ cur, int* __restrict__ csr, int E, int n) {
    int e = blockIdx.x * 256 + threadIdx.x;
    if (e < E) {
        int c = col[e];
        int p = atomicAdd(&cur[row[e]], 1);
        csr[p] = c | (bkt[c] << 19);
    } else if (e < E + n) {
        int nn = e - E;
        int p = atomicAdd(&cur[nn], 1);
        csr[p] = nn | (bkt[nn] << 19);
    }
}

// ---------------------------------------------------------------------------
// fp32 -> bf16 elementwise convert (4 elems/thread)
__global__ void cvt_bf16_k(const float* __restrict__ s, unsigned short* __restrict__ d, int n) {
    int i = (blockIdx.x * 256 + threadIdx.x) * 4;
    if (i < n) {
        float4 v = *(const float4*)(s + i);
        ushort4 o;
        o.x = f2bf(v.x); o.y = f2bf(v.y); o.z = f2bf(v.z); o.w = f2bf(v.w);
        *(ushort4*)(d + i) = o;
    }
}

// ---------------------------------------------------------------------------
// ALL weight transposes (fp32 [K][N] -> bf16 [N][K]) in ONE kernel.
struct TDesc { const float* src; unsigned short* dst; int K; int N; int tileStart; };
struct TPack { TDesc d[13]; int nd; };

__global__ __launch_bounds__(256) void mega_transpose_k(TPack p) {
    __shared__ float tile[32][33];
    const int tb = blockIdx.x;
    int di = 0;
    for (int i = 1; i < 13; ++i)
        if (i < p.nd && p.d[i].tileStart <= tb) di = i;
    const float* __restrict__ src = p.d[di].src;
    unsigned short* __restrict__ dst = p.d[di].dst;
    const int K = p.d[di].K, N = p.d[di].N;
    const int local = tb - p.d[di].tileStart;
    const int tpn = N >> 5;
    const int n0 = (local % tpn) * 32;
    const int k0 = (local / tpn) * 32;
    const int t = threadIdx.x;
    {
        int r = t >> 3, c = (t & 7) * 4;
        float4 v = *(const float4*)(src + (size_t)(k0 + r) * N + n0 + c);
        tile[r][c] = v.x; tile[r][c + 1] = v.y; tile[r][c + 2] = v.z; tile[r][c + 3] = v.w;
    }
    __syncthreads();
    {
        int n = t >> 3, k = (t & 7) * 4;
        ushort4 o;
        o.x = f2bf(tile[k][n]); o.y = f2bf(tile[k + 1][n]);
        o.z = f2bf(tile[k + 2][n]); o.w = f2bf(tile[k + 3][n]);
        *(ushort4*)(dst + (size_t)(n0 + n) * K + k0 + k) = o;
    }
}

// both layers' q|k|v bias concat in one kernel: grid 6 x 256
__global__ void concat_bias2_k(const float* __restrict__ bq, const float* __restrict__ bk,
                               const float* __restrict__ bv,
                               float* __restrict__ d0, float* __restrict__ d1) {
    int t = blockIdx.x * 256 + threadIdx.x;      // 0..1535
    int l = t / 768, u = t - l * 768;
    float v;
    if (u < 256) v = bq[l * DMODEL + u];
    else if (u < 512) v = bk[l * DMODEL + u - 256];
    else v = bv[l * DMODEL + u - 512];
    (l ? d1 : d0)[u] = v;
}

// ---------------------------------------------------------------------------
// bf16 MFMA GEMM: C[M,Nout] = A[M,K](bf16) @ Wt[Nout,K](bf16)^T + bias
// BM=BN=128, BK=32, 256 threads = 4 waves (2x2), wave tile 64x64 = 4x4 frags.
// Staging via global_load_lds width=16 into LINEAR LDS (m97 pattern).
__global__ __launch_bounds__(256) void gemm_bf16_k(
        const unsigned short* __restrict__ A, const unsigned short* __restrict__ Wt,
        const float* __restrict__ bias,
        float* __restrict__ Cf, unsigned short* __restrict__ Cb,
        int M, int K, int Nout,
        const float* __restrict__ emb, const int* __restrict__ bkt, int act) {
    __shared__ unsigned short As[128 * 32];  // linear [row][32k], 64 B/row
    __shared__ unsigned short Bs[128 * 32];
    const int bm = blockIdx.x * 128;
    const int bn = blockIdx.y * 128;
    const int t = threadIdx.x;
    const int wid = t >> 6, lane = t & 63;
    const int wm = wid >> 1, wn = wid & 1;
    const int l16 = lane & 15, kslc = lane >> 4;
    const int srow = lane >> 2, scol = (lane & 3) * 8;

    f32x4 acc[4][4] = {};

    for (int k0 = 0; k0 < K; k0 += 32) {
        const unsigned short* gA = A + (size_t)(bm + wid * 32 + srow) * K + k0 + scol;
        const unsigned short* gB = Wt + (size_t)(bn + wid * 32 + srow) * K + k0 + scol;
        gl16(gA,          &As[(wid * 32) * 32]);
        gl16(gA + 16 * K, &As[(wid * 32 + 16) * 32]);
        gl16(gB,          &Bs[(wid * 32) * 32]);
        gl16(gB + 16 * K, &Bs[(wid * 32 + 16) * 32]);
        __syncthreads();
        short8v a[4], b[4];
        #pragma unroll
        for (int f = 0; f < 4; ++f) {
            a[f] = *(const short8v*)(&As[(wm * 64 + f * 16 + l16) * 32 + kslc * 8]);
            b[f] = *(const short8v*)(&Bs[(wn * 64 + f * 16 + l16) * 32 + kslc * 8]);
        }
        #pragma unroll
        for (int fm = 0; fm < 4; ++fm)
            #pragma unroll
            for (int fn = 0; fn < 4; ++fn)
                acc[fm][fn] = __builtin_amdgcn_mfma_f32_16x16x32_bf16(
                    a[fm], b[fn], acc[fm][fn], 0, 0, 0);
        __syncthreads();
    }

    // epilogue: C/D layout col=lane&15, row=(lane>>4)*4+reg
    #pragma unroll
    for (int fm = 0; fm < 4; ++fm) {
        #pragma unroll
        for (int fn = 0; fn < 4; ++fn) {
            int cc = wn * 64 + fn * 16 + l16;
            int gn = bn + cc;
            float bn_v = bias[gn];
            int rbase = bm + wm * 64 + fm * 16 + (lane >> 4) * 4;
            #pragma unroll
            for (int r = 0; r < 4; ++r) {
                int gm = rbase + r;
                if (gm >= M) continue;
                float v = acc[fm][fn][r] + bn_v;
                if (emb) v += emb[(size_t)bkt[gm] * Nout + gn];
                if (act) v = 0.5f * v * (1.f + erff(v * 0.70710678118654752f));
                if (Cf) Cf[(size_t)gm * Nout + gn] = v;
                if (Cb) Cb[(size_t)gm * Nout + gn] = f2bf(v);
            }
        }
    }
}

// ---------------------------------------------------------------------------
// FUSED GEMM + residual + LayerNorm (Nout = 256 = DMODEL, full row per block):
//   C = A[M,K] @ Wt[256,K]^T + bias ; x = h + C ; h = LN(x)*g+b ; hb = bf16(h)
// BM=128, BN=256, BK=32, 512 threads = 8 waves (2m x 4n), wave tile 64x64.
__global__ __launch_bounds__(512) void gemm_ln_k(
        const unsigned short* __restrict__ A, const unsigned short* __restrict__ Wt,
        const float* __restrict__ bias,
        float* __restrict__ h, unsigned short* __restrict__ hb,
        const float* __restrict__ lng, const float* __restrict__ lnb,
        int M, int K) {
    __shared__ unsigned short As[128 * 32];   //  8 KB
    __shared__ unsigned short Bs[256 * 32];   // 16 KB
    __shared__ float red[128 * 4];            //  2 KB row partials
    const int bm = blockIdx.x * 128;
    const int t = threadIdx.x;
    const int wid = t >> 6, lane = t & 63;
    const int wm = wid >> 2, wn = wid & 3;
    const int l16 = lane & 15, kslc = lane >> 4;
    const int srow = lane >> 2, scol = (lane & 3) * 8;

    f32x4 acc[4][4] = {};

    for (int k0 = 0; k0 < K; k0 += 32) {
        if (wid < 4) {   // waves 0-3 stage A (32 rows each)
            const unsigned short* gA = A + (size_t)(bm + wid * 32 + srow) * K + k0 + scol;
            gl16(gA,          &As[(wid * 32) * 32]);
            gl16(gA + 16 * K, &As[(wid * 32 + 16) * 32]);
        } else {          // waves 4-7 stage B (64 rows each)
            const int w4 = wid - 4;
            const unsigned short* gB = Wt + (size_t)(w4 * 64 + srow) * K + k0 + scol;
            gl16(gB,          &Bs[(w4 * 64) * 32]);
            gl16(gB + 16 * K, &Bs[(w4 * 64 + 16) * 32]);
            gl16(gB + 32 * K, &Bs[(w4 * 64 + 32) * 32]);
            gl16(gB + 48 * K, &Bs[(w4 * 64 + 48) * 32]);
        }
        __syncthreads();
        short8v a[4], bb[4];
        #pragma unroll
        for (int f = 0; f < 4; ++f) {
            a[f]  = *(const short8v*)(&As[(wm * 64 + f * 16 + l16) * 32 + kslc * 8]);
            bb[f] = *(const short8v*)(&Bs[(wn * 64 + f * 16 + l16) * 32 + kslc * 8]);
        }
        #pragma unroll
        for (int fm = 0; fm < 4; ++fm)
            #pragma unroll
            for (int fn = 0; fn < 4; ++fn)
                acc[fm][fn] = __builtin_amdgcn_mfma_f32_16x16x32_bf16(
                    a[fm], bb[fn], acc[fm][fn], 0, 0, 0);
        __syncthreads();
    }

    // x = C + bias + residual   (rows gm>=M carry garbage; never stored)
    #pragma unroll
    for (int fm = 0; fm < 4; ++fm) {
        #pragma unroll
        for (int fn = 0; fn < 4; ++fn) {
            const int gn = wn * 64 + fn * 16 + l16;
            const float bv = bias[gn];
            #pragma unroll
            for (int r = 0; r < 4; ++r) {
                const int gm = bm + wm * 64 + fm * 16 + kslc * 4 + r;
                float v = acc[fm][fn][r] + bv;
                if (gm < M) v += h[(size_t)gm * DMODEL + gn];
                acc[fm][fn][r] = v;
            }
        }
    }

    // phase 1: row means (16-lane shfl -> 4-wave LDS partials)
    float mean[4][4];
    #pragma unroll
    for (int fm = 0; fm < 4; ++fm)
        #pragma unroll
        for (int r = 0; r < 4; ++r) {
            float p = acc[fm][0][r] + acc[fm][1][r] + acc[fm][2][r] + acc[fm][3][r];
            #pragma unroll
            for (int mk = 8; mk >= 1; mk >>= 1) p += __shfl_xor(p, mk);
            mean[fm][r] = p;   // wave partial, valid in all lanes
        }
    if (l16 == 0) {
        #pragma unroll
        for (int fm = 0; fm < 4; ++fm)
            #pragma unroll
            for (int r = 0; r < 4; ++r)
                red[(wm * 64 + fm * 16 + kslc * 4 + r) * 4 + wn] = mean[fm][r];
    }
    __syncthreads();
    #pragma unroll
    for (int fm = 0; fm < 4; ++fm)
        #pragma unroll
        for (int r = 0; r < 4; ++r) {
            const int lr = wm * 64 + fm * 16 + kslc * 4 + r;
            mean[fm][r] = (red[lr * 4] + red[lr * 4 + 1] + red[lr * 4 + 2] + red[lr * 4 + 3])
                          * (1.f / DMODEL);
        }
    __syncthreads();   // red reuse barrier

    // phase 2: row variances E[(x-mu)^2]
    float var[4][4];
    #pragma unroll
    for (int fm = 0; fm < 4; ++fm)
        #pragma unroll
        for (int r = 0; r < 4; ++r) {
            const float mu = mean[fm][r];
            float d0 = acc[fm][0][r] - mu, d1 = acc[fm][1][r] - mu;
            float d2 = acc[fm][2][r] - mu, d3 = acc[fm][3][r] - mu;
            float p = d0 * d0 + d1 * d1 + d2 * d2 + d3 * d3;
            #pragma unroll
            for (int mk = 8; mk >= 1; mk >>= 1) p += __shfl_xor(p, mk);
            var[fm][r] = p;
        }
    if (l16 == 0) {
        #pragma unroll
        for (int fm = 0; fm < 4; ++fm)
            #pragma unroll
            for (int r = 0; r < 4; ++r)
                red[(wm * 64 + fm * 16 + kslc * 4 + r) * 4 + wn] = var[fm][r];
    }
    __syncthreads();
    #pragma unroll
    for (int fm = 0; fm < 4; ++fm)
        #pragma unroll
        for (int r = 0; r < 4; ++r) {
            const int lr = wm * 64 + fm * 16 + kslc * 4 + r;
            var[fm][r] = (red[lr * 4] + red[lr * 4 + 1] + red[lr * 4 + 2] + red[lr * 4 + 3])
                         * (1.f / DMODEL);
        }

    // store: h = (x-mu)*rsqrt(var+eps)*g+b ; hb = bf16(h)
    #pragma unroll
    for (int fm = 0; fm < 4; ++fm) {
        #pragma unroll
        for (int r = 0; r < 4; ++r) {
            const int gm = bm + wm * 64 + fm * 16 + kslc * 4 + r;
            if (gm >= M) continue;
            const float mu = mean[fm][r];
            const float rs = rsqrtf(var[fm][r] + 1e-5f);
            #pragma unroll
            for (int fn = 0; fn < 4; ++fn) {
                const int gn = wn * 64 + fn * 16 + l16;
                float y = (acc[fm][fn][r] - mu) * rs * lng[gn] + lnb[gn];
                h[(size_t)gm * DMODEL + gn] = y;
                hb[(size_t)gm * DMODEL + gn] = f2bf(y);
            }
        }
    }
}

// ---------------------------------------------------------------------------
// Attention over CSR (bucket-packed entries), bf16 QKV per node [Q|K|V].
// Block = 128 threads: head hh = t>>4, dim pair d2 = t&15.
// Online softmax; register-level software pipeline (ping-pong A/B batches).

#define LOADB(CC, KK, VV, SB, J)                                               \
    do {                                                                        \
        _Pragma("unroll")                                                       \
        for (int e = 0; e < UNR; ++e)                                           \
            CC[e] = csr[min((J) + e, s1 - 1)];                                  \
        _Pragma("unroll")                                                       \
        for (int e = 0; e < UNR; ++e) {                                         \
            const unsigned short* base =                                        \
                QKV + (size_t)(CC[e] & 0x7FFFF) * 768 + hh * 32 + d2 * 2;       \
            KK[e] = *(const ushort2*)(base + 256);                              \
            VV[e] = *(const ushort2*)(base + 512);                              \
            SB[e] = sb_i[(CC[e] >> 19) * NHEAD + hh];                           \
        }                                                                       \
    } while (0)

#define COMPUTE(KK, VV, SB, J)                                                 \
    do {                                                                        \
        _Pragma("unroll")                                                       \
        for (int e = 0; e < UNR; ++e) {                                         \
            float p = qx * bf2f(KK[e].x) + qy * bf2f(KK[e].y);                  \
            _Pragma("unroll")                                                   \
            for (int mk = 8; mk >= 1; mk >>= 1) p += __shfl_xor(p, mk);         \
            float sc = p * scale + sbn + SB[e];                                 \
            if ((J) + e < s1) {                                                 \
                float mn = fmaxf(m, sc);                                        \
                float corr = __expf(m - mn);                                    \
                float es = __expf(sc - mn);                                     \
                s = s * corr + es;                                              \
                ax = ax * corr + es * bf2f(VV[e].x);                            \
                ay = ay * corr + es * bf2f(VV[e].y);                            \
                m = mn;                                                         \
            }                                                                   \
        }                                                                       \
    } while (0)

__global__ __launch_bounds__(128) void attn_bf16_k(
        const unsigned short* __restrict__ QKV,
        const int* __restrict__ off, const int* __restrict__ csr,
        const int* __restrict__ bkt, const float* __restrict__ sb_i,
        unsigned short* __restrict__ aggb) {
    const int node = blockIdx.x;
    const int t = threadIdx.x;
    const int hh = t >> 4, d2 = t & 15;
    const int s0 = off[node], s1 = off[node + 1];
    const ushort2 q2 = *(const ushort2*)(QKV + (size_t)node * 768 + hh * 32 + d2 * 2);
    const float qx = bf2f(q2.x), qy = bf2f(q2.y);
    const float sbn = sb_i[bkt[node] * NHEAD + hh];
    const float scale = 0.17677669529663689f;  // 32^-0.5
    float m = -1e30f, s = 0.f, ax = 0.f, ay = 0.f;

    int ccA[UNR]; ushort2 kkA[UNR], vvA[UNR]; float sbA[UNR];
    int ccB[UNR]; ushort2 kkB[UNR], vvB[UNR]; float sbB[UNR];

    LOADB(ccA, kkA, vvA, sbA, s0);
    for (int j = s0; j < s1; j += 2 * UNR) {
        LOADB(ccB, kkB, vvB, sbB, j + UNR);
        COMPUTE(kkA, vvA, sbA, j);
        LOADB(ccA, kkA, vvA, sbA, j + 2 * UNR);
        COMPUTE(kkB, vvB, sbB, j + UNR);
    }

    float inv = 1.f / fmaxf(s, 1e-12f);
    ushort2 o;
    o.x = f2bf(ax * inv); o.y = f2bf(ay * inv);
    *(ushort2*)(aggb + (size_t)node * DMODEL + hh * 32 + d2 * 2) = o;
}

// ---------------------------------------------------------------------------
extern "C" void kernel_launch(void* const* d_in, const int* in_sizes, int n_in,
                              void* d_out, int out_size, void* d_ws, size_t ws_size,
                              hipStream_t stream) {
    const float* x      = (const float*)d_in[0];
    const int*   row    = (const int*)d_in[1];
    const int*   col    = (const int*)d_in[2];
    const float* Wx     = (const float*)d_in[3];
    const float* bx     = (const float*)d_in[4];
    const float* degemb = (const float*)d_in[5];
    const float* sb     = (const float*)d_in[6];
    const float* Wq     = (const float*)d_in[7];
    const float* bq     = (const float*)d_in[8];
    const float* Wk     = (const float*)d_in[9];
    const float* bk     = (const float*)d_in[10];
    const float* Wv     = (const float*)d_in[11];
    const float* bv     = (const float*)d_in[12];
    const float* Wo     = (const float*)d_in[13];
    const float* bo     = (const float*)d_in[14];
    const float* ln1g   = (const float*)d_in[15];
    const float* ln1b   = (const float*)d_in[16];
    const float* ln2g   = (const float*)d_in[17];
    const float* ln2b   = (const float*)d_in[18];
    const float* W1     = (const float*)d_in[19];
    const float* b1     = (const float*)d_in[20];
    const float* W2     = (const float*)d_in[21];
    const float* b2     = (const float*)d_in[22];

    const int Nn = NNODES, E = NEDGES;
    float* h = (float*)d_out;

    // ---- workspace arena (bytes). A-operand matrices padded to NPAD rows. ----
    char* w = (char*)d_ws;
    unsigned short* hb   = (unsigned short*)w; w += (size_t)NPAD * DMODEL * 2;
    unsigned short* QKVb = (unsigned short*)w; w += (size_t)Nn * 768 * 2;
    unsigned short* AGGb = (unsigned short*)w; w += (size_t)NPAD * DMODEL * 2;
    unsigned short* FFb  = (unsigned short*)w; w += (size_t)NPAD * DFF * 2;
    unsigned short* xb   = (unsigned short*)w; w += (size_t)NPAD * INC * 2;
    unsigned short* Wxt  = (unsigned short*)w; w += (size_t)DMODEL * INC * 2;
    unsigned short* Wqkvt[NLAYER]; float* bqkv[NLAYER];
    unsigned short *Wot[NLAYER], *W1t[NLAYER], *W2t[NLAYER];
    for (int l = 0; l < NLAYER; ++l) {
        Wqkvt[l] = (unsigned short*)w; w += (size_t)768 * DMODEL * 2;
        bqkv[l]  = (float*)w;          w += 768 * 4;
        Wot[l]   = (unsigned short*)w; w += (size_t)DMODEL * DMODEL * 2;
        W1t[l]   = (unsigned short*)w; w += (size_t)DFF * DMODEL * 2;
        W2t[l]   = (unsigned short*)w; w += (size_t)DMODEL * DFF * 2;
    }
    int* CSR = (int*)w; w += (size_t)ETOT * 4;
    int* OFF = (int*)w; w += (Nn + 1) * 4;
    int* CUR = (int*)w; w += Nn * 4;
    int* DEG = (int*)w; w += Nn * 4;
    int* BKT = (int*)w; w += Nn * 4;

    // ---- graph preprocessing ----
    hipMemsetAsync(DEG, 0, Nn * sizeof(int), stream);
    count_deg_k<<<(E + 255) / 256, 256, 0, stream>>>(row, DEG, E);
    scan_offsets_k<<<1, 1024, 0, stream>>>(DEG, OFF, CUR, BKT, Nn);
    csr_fill_k<<<(E + Nn + 255) / 256, 256, 0, stream>>>(row, col, BKT, CUR, CSR, E, Nn);

    // ---- input convert + ALL weight transposes (1 kernel) + bias concat (1 kernel) ----
    cvt_bf16_k<<<((size_t)Nn * INC / 4 + 255) / 256, 256, 0, stream>>>(x, xb, Nn * INC);
    {
        TPack pk; int nd = 0, tt = 0;
        auto add = [&](const float* s, unsigned short* d, int K, int N) {
            pk.d[nd].src = s; pk.d[nd].dst = d; pk.d[nd].K = K; pk.d[nd].N = N;
            pk.d[nd].tileStart = tt;
            tt += (K / 32) * (N / 32);
            ++nd;
        };
        const size_t DD = (size_t)DMODEL * DMODEL;
        add(Wx, Wxt, INC, DMODEL);
        for (int l = 0; l < NLAYER; ++l) {
            add(Wq + l * DD, Wqkvt[l],                DMODEL, DMODEL);
            add(Wk + l * DD, Wqkvt[l] + 256 * DMODEL, DMODEL, DMODEL);
            add(Wv + l * DD, Wqkvt[l] + 512 * DMODEL, DMODEL, DMODEL);
            add(Wo + l * DD, Wot[l], DMODEL, DMODEL);
            add(W1 + (size_t)l * DMODEL * DFF, W1t[l], DMODEL, DFF);
            add(W2 + (size_t)l * DFF * DMODEL, W2t[l], DFF, DMODEL);
        }
        pk.nd = nd;  // 13
        mega_transpose_k<<<tt, 256, 0, stream>>>(pk);  // tt = 1056
        concat_bias2_k<<<6, 256, 0, stream>>>(bq, bk, bv, bqkv[0], bqkv[1]);
    }

    const int MB = (Nn + 127) / 128;  // 157

    // ---- embedding: h = x @ Wx + bx + deg_emb[bucket] ; also hb ----
    {
        dim3 grid(MB, DMODEL / 128);
        gemm_bf16_k<<<grid, 256, 0, stream>>>(xb, Wxt, bx, h, hb, Nn, INC, DMODEL,
                                              degemb, BKT, 0);
    }

    // ---- layers ----
    for (int l = 0; l < NLAYER; ++l) {
        const float* sb_i = sb + (size_t)l * NBUCKET * NHEAD;
        dim3 gQKV(MB, 768 / 128);
        dim3 gF(MB, DFF / 128);

        gemm_bf16_k<<<gQKV, 256, 0, stream>>>(hb, Wqkvt[l], bqkv[l], nullptr, QKVb,
                                              Nn, DMODEL, 768, nullptr, nullptr, 0);
        attn_bf16_k<<<Nn, 128, 0, stream>>>(QKVb, OFF, CSR, BKT, sb_i, AGGb);
        gemm_ln_k<<<MB, 512, 0, stream>>>(AGGb, Wot[l], bo + (size_t)l * DMODEL,
                                          h, hb, ln1g + (size_t)l * DMODEL,
                                          ln1b + (size_t)l * DMODEL, Nn, DMODEL);
        gemm_bf16_k<<<gF, 256, 0, stream>>>(hb, W1t[l], b1 + (size_t)l * DFF,
                                            nullptr, FFb, Nn, DMODEL, DFF,
                                            nullptr, nullptr, 1);
        gemm_ln_k<<<MB, 512, 0, stream>>>(FFb, W2t[l], b2 + (size_t)l * DMODEL,
                                          h, hb, ln2g + (size_t)l * DMODEL,
                                          ln2b + (size_t)l * DMODEL, Nn, DFF);
    }
}

// Round 14
// 594.980 us; speedup vs baseline: 2.7481x; 1.0635x over previous
//
#include <hip/hip_runtime.h>
#include <hip/hip_bf16.h>
#include <math.h>

#define NNODES 20000
#define NPAD   20096   // 157*128: A-operand row padding for global_load_lds safety
#define NEDGES 320000
#define INC 128
#define DMODEL 256
#define NHEAD 8
#define DHEAD 32
#define NLAYER 2
#define NBUCKET 64
#define DFF 512
#define ETOT (NEDGES + NNODES)
#define UNR 8

typedef __attribute__((ext_vector_type(8))) short short8v;
typedef __attribute__((ext_vector_type(4))) float f32x4;

__device__ __forceinline__ float bf2f(unsigned short u) {
    return __uint_as_float(((unsigned int)u) << 16);
}
__device__ __forceinline__ unsigned short f2bf(float f) {
    unsigned int u = __float_as_uint(f);
    unsigned int r = (u + 0x7FFFu + ((u >> 16) & 1u)) >> 16;
    return (unsigned short)r;
}
// async global->LDS, 16B per lane; LDS dest = wave-uniform base + lane*16
__device__ __forceinline__ void gl16(const unsigned short* g, unsigned short* l) {
    __builtin_amdgcn_global_load_lds(
        (const __attribute__((address_space(1))) void*)g,
        (__attribute__((address_space(3))) void*)l, 16, 0, 0);
}

// ---------------------------------------------------------------------------
// Graph preprocessing
__global__ void count_deg_k(const int* __restrict__ row, int* __restrict__ deg, int E) {
    int e = blockIdx.x * 256 + threadIdx.x;
    if (e < E) atomicAdd(&deg[row[e]], 1);
}

// exclusive scan of (deg+1) -> off, cur; also bucket = clip(floor(log2(max(deg,1))),1,63)
__global__ __launch_bounds__(1024) void scan_offsets_k(const int* __restrict__ deg,
                                                       int* __restrict__ off,
                                                       int* __restrict__ cur,
                                                       int* __restrict__ bkt, int n) {
    const int T = 1024;
    int t = threadIdx.x;
    int chunk = (n + T - 1) / T;
    int base = t * chunk;
    int s = 0;
    for (int i = 0; i < chunk; ++i) {
        int idx = base + i;
        if (idx < n) {
            int d = deg[idx];
            int dd = d < 1 ? 1 : d;
            int b = 31 - __clz(dd);
            bkt[idx] = min(max(b, 1), NBUCKET - 1);
            s += d + 1;
        }
    }
    __shared__ int ps[1024];
    ps[t] = s;
    __syncthreads();
    for (int d = 1; d < T; d <<= 1) {
        int v = (t >= d) ? ps[t - d] : 0;
        __syncthreads();
        ps[t] += v;
        __syncthreads();
    }
    int run = (t == 0) ? 0 : ps[t - 1];
    for (int i = 0; i < chunk; ++i) {
        int idx = base + i;
        if (idx < n) {
            off[idx] = run; cur[idx] = run;
            run += deg[idx] + 1;
        }
    }
    if (t == T - 1) off[n] = ps[T - 1];
}

// fill CSR columns PACKED with the neighbor's degree bucket: col | bkt[col]<<19
__global__ void csr_fill_k(const int* __restrict__ row, const int* __restrict__ col,
                           const int* __restrict__ bkt,
                           int* __restrict__ cur, int* __restrict__ csr, int E, int n) {
    int e = blockIdx.x * 256 + threadIdx.x;
    if (e < E) {
        int c = col[e];
        int p = atomicAdd(&cur[row[e]], 1);
        csr[p] = c | (bkt[c] << 19);
    } else if (e < E + n) {
        int nn = e - E;
        int p = atomicAdd(&cur[nn], 1);
        csr[p] = nn | (bkt[nn] << 19);
    }
}

// ---------------------------------------------------------------------------
// fp32 -> bf16 elementwise convert (4 elems/thread)
__global__ void cvt_bf16_k(const float* __restrict__ s, unsigned short* __restrict__ d, int n) {
    int i = (blockIdx.x * 256 + threadIdx.x) * 4;
    if (i < n) {
        float4 v = *(const float4*)(s + i);
        ushort4 o;
        o.x = f2bf(v.x); o.y = f2bf(v.y); o.z = f2bf(v.z); o.w = f2bf(v.w);
        *(ushort4*)(d + i) = o;
    }
}

// ---------------------------------------------------------------------------
// ALL weight transposes (fp32 [K][N] -> bf16 [N][K]) in ONE kernel.
struct TDesc { const float* src; unsigned short* dst; int K; int N; int tileStart; };
struct TPack { TDesc d[13]; int nd; };

__global__ __launch_bounds__(256) void mega_transpose_k(TPack p) {
    __shared__ float tile[32][33];
    const int tb = blockIdx.x;
    int di = 0;
    for (int i = 1; i < 13; ++i)
        if (i < p.nd && p.d[i].tileStart <= tb) di = i;
    const float* __restrict__ src = p.d[di].src;
    unsigned short* __restrict__ dst = p.d[di].dst;
    const int K = p.d[di].K, N = p.d[di].N;
    const int local = tb - p.d[di].tileStart;
    const int tpn = N >> 5;
    const int n0 = (local % tpn) * 32;
    const int k0 = (local / tpn) * 32;
    const int t = threadIdx.x;
    {
        int r = t >> 3, c = (t & 7) * 4;
        float4 v = *(const float4*)(src + (size_t)(k0 + r) * N + n0 + c);
        tile[r][c] = v.x; tile[r][c + 1] = v.y; tile[r][c + 2] = v.z; tile[r][c + 3] = v.w;
    }
    __syncthreads();
    {
        int n = t >> 3, k = (t & 7) * 4;
        ushort4 o;
        o.x = f2bf(tile[k][n]); o.y = f2bf(tile[k + 1][n]);
        o.z = f2bf(tile[k + 2][n]); o.w = f2bf(tile[k + 3][n]);
        *(ushort4*)(dst + (size_t)(n0 + n) * K + k0 + k) = o;
    }
}

// both layers' q|k|v bias concat in one kernel: grid 6 x 256
__global__ void concat_bias2_k(const float* __restrict__ bq, const float* __restrict__ bk,
                               const float* __restrict__ bv,
                               float* __restrict__ d0, float* __restrict__ d1) {
    int t = blockIdx.x * 256 + threadIdx.x;      // 0..1535
    int l = t / 768, u = t - l * 768;
    float v;
    if (u < 256) v = bq[l * DMODEL + u];
    else if (u < 512) v = bk[l * DMODEL + u - 256];
    else v = bv[l * DMODEL + u - 512];
    (l ? d1 : d0)[u] = v;
}

// ---------------------------------------------------------------------------
// bf16 MFMA GEMM: C[M,Nout] = A[M,K](bf16) @ Wt[Nout,K](bf16)^T + bias
// BM=BN=128, BK=32, 256 threads = 4 waves (2x2), wave tile 64x64 = 4x4 frags.
__global__ __launch_bounds__(256) void gemm_bf16_k(
        const unsigned short* __restrict__ A, const unsigned short* __restrict__ Wt,
        const float* __restrict__ bias,
        float* __restrict__ Cf, unsigned short* __restrict__ Cb,
        int M, int K, int Nout,
        const float* __restrict__ emb, const int* __restrict__ bkt, int act) {
    __shared__ unsigned short As[128 * 32];  // linear [row][32k], 64 B/row
    __shared__ unsigned short Bs[128 * 32];
    const int bm = blockIdx.x * 128;
    const int bn = blockIdx.y * 128;
    const int t = threadIdx.x;
    const int wid = t >> 6, lane = t & 63;
    const int wm = wid >> 1, wn = wid & 1;
    const int l16 = lane & 15, kslc = lane >> 4;
    const int srow = lane >> 2, scol = (lane & 3) * 8;

    f32x4 acc[4][4] = {};

    for (int k0 = 0; k0 < K; k0 += 32) {
        const unsigned short* gA = A + (size_t)(bm + wid * 32 + srow) * K + k0 + scol;
        const unsigned short* gB = Wt + (size_t)(bn + wid * 32 + srow) * K + k0 + scol;
        gl16(gA,          &As[(wid * 32) * 32]);
        gl16(gA + 16 * K, &As[(wid * 32 + 16) * 32]);
        gl16(gB,          &Bs[(wid * 32) * 32]);
        gl16(gB + 16 * K, &Bs[(wid * 32 + 16) * 32]);
        __syncthreads();
        short8v a[4], b[4];
        #pragma unroll
        for (int f = 0; f < 4; ++f) {
            a[f] = *(const short8v*)(&As[(wm * 64 + f * 16 + l16) * 32 + kslc * 8]);
            b[f] = *(const short8v*)(&Bs[(wn * 64 + f * 16 + l16) * 32 + kslc * 8]);
        }
        #pragma unroll
        for (int fm = 0; fm < 4; ++fm)
            #pragma unroll
            for (int fn = 0; fn < 4; ++fn)
                acc[fm][fn] = __builtin_amdgcn_mfma_f32_16x16x32_bf16(
                    a[fm], b[fn], acc[fm][fn], 0, 0, 0);
        __syncthreads();
    }

    // epilogue: C/D layout col=lane&15, row=(lane>>4)*4+reg
    #pragma unroll
    for (int fm = 0; fm < 4; ++fm) {
        #pragma unroll
        for (int fn = 0; fn < 4; ++fn) {
            int cc = wn * 64 + fn * 16 + l16;
            int gn = bn + cc;
            float bn_v = bias[gn];
            int rbase = bm + wm * 64 + fm * 16 + (lane >> 4) * 4;
            #pragma unroll
            for (int r = 0; r < 4; ++r) {
                int gm = rbase + r;
                if (gm >= M) continue;
                float v = acc[fm][fn][r] + bn_v;
                if (emb) v += emb[(size_t)bkt[gm] * Nout + gn];
                if (act) v = 0.5f * v * (1.f + erff(v * 0.70710678118654752f));
                if (Cf) Cf[(size_t)gm * Nout + gn] = v;
                if (Cb) Cb[(size_t)gm * Nout + gn] = f2bf(v);
            }
        }
    }
}

// ---------------------------------------------------------------------------
// FUSED GEMM + residual + LayerNorm (Nout = 256 = DMODEL, full row per block):
//   C = A[M,K] @ Wt[256,K]^T + bias ; x = h + C ; h = LN(x)*g+b ; hb = bf16(h)
// BM=64, BN=256, BK=32, 512 threads = 8 waves (2m x 4n), wave tile 32x64.
// Grid = ceil(M/64) = 313 blocks (2x the old BM=128 parallelism).
__global__ __launch_bounds__(512) void gemm_ln_k(
        const unsigned short* __restrict__ A, const unsigned short* __restrict__ Wt,
        const float* __restrict__ bias,
        float* __restrict__ h, unsigned short* __restrict__ hb,
        const float* __restrict__ lng, const float* __restrict__ lnb,
        int M, int K) {
    __shared__ unsigned short As[64 * 32];    //  4 KB
    __shared__ unsigned short Bs[256 * 32];   // 16 KB
    __shared__ float red[64 * 4];             //  1 KB row partials
    const int bm = blockIdx.x * 64;
    const int t = threadIdx.x;
    const int wid = t >> 6, lane = t & 63;
    const int wm = wid >> 2, wn = wid & 3;
    const int l16 = lane & 15, kslc = lane >> 4;
    const int srow = lane >> 2, scol = (lane & 3) * 8;

    f32x4 acc[2][4] = {};

    for (int k0 = 0; k0 < K; k0 += 32) {
        // B: every wave stages 32 rows (2 gl16); A: waves 0-3 stage 16 rows (1 gl16)
        {
            const unsigned short* gB = Wt + (size_t)(wid * 32 + srow) * K + k0 + scol;
            gl16(gB,          &Bs[(wid * 32) * 32]);
            gl16(gB + 16 * K, &Bs[(wid * 32 + 16) * 32]);
        }
        if (wid < 4) {
            const unsigned short* gA = A + (size_t)(bm + wid * 16 + srow) * K + k0 + scol;
            gl16(gA, &As[(wid * 16) * 32]);
        }
        __syncthreads();
        short8v a[2], bb[4];
        #pragma unroll
        for (int f = 0; f < 2; ++f)
            a[f]  = *(const short8v*)(&As[(wm * 32 + f * 16 + l16) * 32 + kslc * 8]);
        #pragma unroll
        for (int f = 0; f < 4; ++f)
            bb[f] = *(const short8v*)(&Bs[(wn * 64 + f * 16 + l16) * 32 + kslc * 8]);
        #pragma unroll
        for (int fm = 0; fm < 2; ++fm)
            #pragma unroll
            for (int fn = 0; fn < 4; ++fn)
                acc[fm][fn] = __builtin_amdgcn_mfma_f32_16x16x32_bf16(
                    a[fm], bb[fn], acc[fm][fn], 0, 0, 0);
        __syncthreads();
    }

    // x = C + bias + residual   (rows gm>=M carry garbage; never stored)
    #pragma unroll
    for (int fm = 0; fm < 2; ++fm) {
        #pragma unroll
        for (int fn = 0; fn < 4; ++fn) {
            const int gn = wn * 64 + fn * 16 + l16;
            const float bv = bias[gn];
            #pragma unroll
            for (int r = 0; r < 4; ++r) {
                const int gm = bm + wm * 32 + fm * 16 + kslc * 4 + r;
                float v = acc[fm][fn][r] + bv;
                if (gm < M) v += h[(size_t)gm * DMODEL + gn];
                acc[fm][fn][r] = v;
            }
        }
    }

    // phase 1: row means (16-lane shfl -> 4-wave LDS partials)
    float mean[2][4];
    #pragma unroll
    for (int fm = 0; fm < 2; ++fm)
        #pragma unroll
        for (int r = 0; r < 4; ++r) {
            float p = acc[fm][0][r] + acc[fm][1][r] + acc[fm][2][r] + acc[fm][3][r];
            #pragma unroll
            for (int mk = 8; mk >= 1; mk >>= 1) p += __shfl_xor(p, mk);
            mean[fm][r] = p;   // wave partial, valid in all lanes
        }
    if (l16 == 0) {
        #pragma unroll
        for (int fm = 0; fm < 2; ++fm)
            #pragma unroll
            for (int r = 0; r < 4; ++r)
                red[(wm * 32 + fm * 16 + kslc * 4 + r) * 4 + wn] = mean[fm][r];
    }
    __syncthreads();
    #pragma unroll
    for (int fm = 0; fm < 2; ++fm)
        #pragma unroll
        for (int r = 0; r < 4; ++r) {
            const int lr = wm * 32 + fm * 16 + kslc * 4 + r;
            mean[fm][r] = (red[lr * 4] + red[lr * 4 + 1] + red[lr * 4 + 2] + red[lr * 4 + 3])
                          * (1.f / DMODEL);
        }
    __syncthreads();   // red reuse barrier

    // phase 2: row variances E[(x-mu)^2]
    float var[2][4];
    #pragma unroll
    for (int fm = 0; fm < 2; ++fm)
        #pragma unroll
        for (int r = 0; r < 4; ++r) {
            const float mu = mean[fm][r];
            float d0 = acc[fm][0][r] - mu, d1 = acc[fm][1][r] - mu;
            float d2 = acc[fm][2][r] - mu, d3 = acc[fm][3][r] - mu;
            float p = d0 * d0 + d1 * d1 + d2 * d2 + d3 * d3;
            #pragma unroll
            for (int mk = 8; mk >= 1; mk >>= 1) p += __shfl_xor(p, mk);
            var[fm][r] = p;
        }
    if (l16 == 0) {
        #pragma unroll
        for (int fm = 0; fm < 2; ++fm)
            #pragma unroll
            for (int r = 0; r < 4; ++r)
                red[(wm * 32 + fm * 16 + kslc * 4 + r) * 4 + wn] = var[fm][r];
    }
    __syncthreads();
    #pragma unroll
    for (int fm = 0; fm < 2; ++fm)
        #pragma unroll
        for (int r = 0; r < 4; ++r) {
            const int lr = wm * 32 + fm * 16 + kslc * 4 + r;
            var[fm][r] = (red[lr * 4] + red[lr * 4 + 1] + red[lr * 4 + 2] + red[lr * 4 + 3])
                         * (1.f / DMODEL);
        }

    // store: h = (x-mu)*rsqrt(var+eps)*g+b ; hb = bf16(h)
    #pragma unroll
    for (int fm = 0; fm < 2; ++fm) {
        #pragma unroll
        for (int r = 0; r < 4; ++r) {
            const int gm = bm + wm * 32 + fm * 16 + kslc * 4 + r;
            if (gm >= M) continue;
            const float mu = mean[fm][r];
            const float rs = rsqrtf(var[fm][r] + 1e-5f);
            #pragma unroll
            for (int fn = 0; fn < 4; ++fn) {
                const int gn = wn * 64 + fn * 16 + l16;
                float y = (acc[fm][fn][r] - mu) * rs * lng[gn] + lnb[gn];
                h[(size_t)gm * DMODEL + gn] = y;
                hb[(size_t)gm * DMODEL + gn] = f2bf(y);
            }
        }
    }
}

// ---------------------------------------------------------------------------
// Attention over CSR (bucket-packed entries), bf16 QKV per node [Q|K|V].
// Block = 128 threads: head hh = t>>4, dim pair d2 = t&15.
// Online softmax; register-level software pipeline (ping-pong A/B batches).

#define LOADB(CC, KK, VV, SB, J)                                               \
    do {                                                                        \
        _Pragma("unroll")                                                       \
        for (int e = 0; e < UNR; ++e)                                           \
            CC[e] = csr[min((J) + e, s1 - 1)];                                  \
        _Pragma("unroll")                                                       \
        for (int e = 0; e < UNR; ++e) {                                         \
            const unsigned short* base =                                        \
                QKV + (size_t)(CC[e] & 0x7FFFF) * 768 + hh * 32 + d2 * 2;       \
            KK[e] = *(const ushort2*)(base + 256);                              \
            VV[e] = *(const ushort2*)(base + 512);                              \
            SB[e] = sb_i[(CC[e] >> 19) * NHEAD + hh];                           \
        }                                                                       \
    } while (0)

#define COMPUTE(KK, VV, SB, J)                                                 \
    do {                                                                        \
        _Pragma("unroll")                                                       \
        for (int e = 0; e < UNR; ++e) {                                         \
            float p = qx * bf2f(KK[e].x) + qy * bf2f(KK[e].y);                  \
            _Pragma("unroll")                                                   \
            for (int mk = 8; mk >= 1; mk >>= 1) p += __shfl_xor(p, mk);         \
            float sc = p * scale + sbn + SB[e];                                 \
            if ((J) + e < s1) {                                                 \
                float mn = fmaxf(m, sc);                                        \
                float corr = __expf(m - mn);                                    \
                float es = __expf(sc - mn);                                     \
                s = s * corr + es;                                              \
                ax = ax * corr + es * bf2f(VV[e].x);                            \
                ay = ay * corr + es * bf2f(VV[e].y);                            \
                m = mn;                                                         \
            }                                                                   \
        }                                                                       \
    } while (0)

__global__ __launch_bounds__(128) void attn_bf16_k(
        const unsigned short* __restrict__ QKV,
        const int* __restrict__ off, const int* __restrict__ csr,
        const int* __restrict__ bkt, const float* __restrict__ sb_i,
        unsigned short* __restrict__ aggb) {
    const int node = blockIdx.x;
    const int t = threadIdx.x;
    const int hh = t >> 4, d2 = t & 15;
    const int s0 = off[node], s1 = off[node + 1];
    const ushort2 q2 = *(const ushort2*)(QKV + (size_t)node * 768 + hh * 32 + d2 * 2);
    const float qx = bf2f(q2.x), qy = bf2f(q2.y);
    const float sbn = sb_i[bkt[node] * NHEAD + hh];
    const float scale = 0.17677669529663689f;  // 32^-0.5
    float m = -1e30f, s = 0.f, ax = 0.f, ay = 0.f;

    int ccA[UNR]; ushort2 kkA[UNR], vvA[UNR]; float sbA[UNR];
    int ccB[UNR]; ushort2 kkB[UNR], vvB[UNR]; float sbB[UNR];

    LOADB(ccA, kkA, vvA, sbA, s0);
    for (int j = s0; j < s1; j += 2 * UNR) {
        LOADB(ccB, kkB, vvB, sbB, j + UNR);
        COMPUTE(kkA, vvA, sbA, j);
        LOADB(ccA, kkA, vvA, sbA, j + 2 * UNR);
        COMPUTE(kkB, vvB, sbB, j + UNR);
    }

    float inv = 1.f / fmaxf(s, 1e-12f);
    ushort2 o;
    o.x = f2bf(ax * inv); o.y = f2bf(ay * inv);
    *(ushort2*)(aggb + (size_t)node * DMODEL + hh * 32 + d2 * 2) = o;
}

// ---------------------------------------------------------------------------
extern "C" void kernel_launch(void* const* d_in, const int* in_sizes, int n_in,
                              void* d_out, int out_size, void* d_ws, size_t ws_size,
                              hipStream_t stream) {
    const float* x      = (const float*)d_in[0];
    const int*   row    = (const int*)d_in[1];
    const int*   col    = (const int*)d_in[2];
    const float* Wx     = (const float*)d_in[3];
    const float* bx     = (const float*)d_in[4];
    const float* degemb = (const float*)d_in[5];
    const float* sb     = (const float*)d_in[6];
    const float* Wq     = (const float*)d_in[7];
    const float* bq     = (const float*)d_in[8];
    const float* Wk     = (const float*)d_in[9];
    const float* bk     = (const float*)d_in[10];
    const float* Wv     = (const float*)d_in[11];
    const float* bv     = (const float*)d_in[12];
    const float* Wo     = (const float*)d_in[13];
    const float* bo     = (const float*)d_in[14];
    const float* ln1g   = (const float*)d_in[15];
    const float* ln1b   = (const float*)d_in[16];
    const float* ln2g   = (const float*)d_in[17];
    const float* ln2b   = (const float*)d_in[18];
    const float* W1     = (const float*)d_in[19];
    const float* b1     = (const float*)d_in[20];
    const float* W2     = (const float*)d_in[21];
    const float* b2     = (const float*)d_in[22];

    const int Nn = NNODES, E = NEDGES;
    float* h = (float*)d_out;

    // ---- workspace arena (bytes). A-operand matrices padded to NPAD rows. ----
    char* w = (char*)d_ws;
    unsigned short* hb   = (unsigned short*)w; w += (size_t)NPAD * DMODEL * 2;
    unsigned short* QKVb = (unsigned short*)w; w += (size_t)Nn * 768 * 2;
    unsigned short* AGGb = (unsigned short*)w; w += (size_t)NPAD * DMODEL * 2;
    unsigned short* FFb  = (unsigned short*)w; w += (size_t)NPAD * DFF * 2;
    unsigned short* xb   = (unsigned short*)w; w += (size_t)NPAD * INC * 2;
    unsigned short* Wxt  = (unsigned short*)w; w += (size_t)DMODEL * INC * 2;
    unsigned short* Wqkvt[NLAYER]; float* bqkv[NLAYER];
    unsigned short *Wot[NLAYER], *W1t[NLAYER], *W2t[NLAYER];
    for (int l = 0; l < NLAYER; ++l) {
        Wqkvt[l] = (unsigned short*)w; w += (size_t)768 * DMODEL * 2;
        bqkv[l]  = (float*)w;          w += 768 * 4;
        Wot[l]   = (unsigned short*)w; w += (size_t)DMODEL * DMODEL * 2;
        W1t[l]   = (unsigned short*)w; w += (size_t)DFF * DMODEL * 2;
        W2t[l]   = (unsigned short*)w; w += (size_t)DMODEL * DFF * 2;
    }
    int* CSR = (int*)w; w += (size_t)ETOT * 4;
    int* OFF = (int*)w; w += (Nn + 1) * 4;
    int* CUR = (int*)w; w += Nn * 4;
    int* DEG = (int*)w; w += Nn * 4;
    int* BKT = (int*)w; w += Nn * 4;

    // ---- graph preprocessing ----
    hipMemsetAsync(DEG, 0, Nn * sizeof(int), stream);
    count_deg_k<<<(E + 255) / 256, 256, 0, stream>>>(row, DEG, E);
    scan_offsets_k<<<1, 1024, 0, stream>>>(DEG, OFF, CUR, BKT, Nn);
    csr_fill_k<<<(E + Nn + 255) / 256, 256, 0, stream>>>(row, col, BKT, CUR, CSR, E, Nn);

    // ---- input convert + ALL weight transposes (1 kernel) + bias concat (1 kernel) ----
    cvt_bf16_k<<<((size_t)Nn * INC / 4 + 255) / 256, 256, 0, stream>>>(x, xb, Nn * INC);
    {
        TPack pk; int nd = 0, tt = 0;
        auto add = [&](const float* s, unsigned short* d, int K, int N) {
            pk.d[nd].src = s; pk.d[nd].dst = d; pk.d[nd].K = K; pk.d[nd].N = N;
            pk.d[nd].tileStart = tt;
            tt += (K / 32) * (N / 32);
            ++nd;
        };
        const size_t DD = (size_t)DMODEL * DMODEL;
        add(Wx, Wxt, INC, DMODEL);
        for (int l = 0; l < NLAYER; ++l) {
            add(Wq + l * DD, Wqkvt[l],                DMODEL, DMODEL);
            add(Wk + l * DD, Wqkvt[l] + 256 * DMODEL, DMODEL, DMODEL);
            add(Wv + l * DD, Wqkvt[l] + 512 * DMODEL, DMODEL, DMODEL);
            add(Wo + l * DD, Wot[l], DMODEL, DMODEL);
            add(W1 + (size_t)l * DMODEL * DFF, W1t[l], DMODEL, DFF);
            add(W2 + (size_t)l * DFF * DMODEL, W2t[l], DFF, DMODEL);
        }
        pk.nd = nd;  // 13
        mega_transpose_k<<<tt, 256, 0, stream>>>(pk);  // tt = 1056
        concat_bias2_k<<<6, 256, 0, stream>>>(bq, bk, bv, bqkv[0], bqkv[1]);
    }

    const int MB = (Nn + 127) / 128;   // 157
    const int MB64 = (Nn + 63) / 64;   // 313

    // ---- embedding: h = x @ Wx + bx + deg_emb[bucket] ; also hb ----
    {
        dim3 grid(MB, DMODEL / 128);
        gemm_bf16_k<<<grid, 256, 0, stream>>>(xb, Wxt, bx, h, hb, Nn, INC, DMODEL,
                                              degemb, BKT, 0);
    }

    // ---- layers ----
    for (int l = 0; l < NLAYER; ++l) {
        const float* sb_i = sb + (size_t)l * NBUCKET * NHEAD;
        dim3 gQKV(MB, 768 / 128);
        dim3 gF(MB, DFF / 128);

        gemm_bf16_k<<<gQKV, 256, 0, stream>>>(hb, Wqkvt[l], bqkv[l], nullptr, QKVb,
                                              Nn, DMODEL, 768, nullptr, nullptr, 0);
        attn_bf16_k<<<Nn, 128, 0, stream>>>(QKVb, OFF, CSR, BKT, sb_i, AGGb);
        gemm_ln_k<<<MB64, 512, 0, stream>>>(AGGb, Wot[l], bo + (size_t)l * DMODEL,
                                            h, hb, ln1g + (size_t)l * DMODEL,
                                            ln1b + (size_t)l * DMODEL, Nn, DMODEL);
        gemm_bf16_k<<<gF, 256, 0, stream>>>(hb, W1t[l], b1 + (size_t)l * DFF,
                                            nullptr, FFb, Nn, DMODEL, DFF,
                                            nullptr, nullptr, 1);
        gemm_ln_k<<<MB64, 512, 0, stream>>>(FFb, W2t[l], b2 + (size_t)l * DMODEL,
                                            h, hb, ln2g + (size_t)l * DMODEL,
                                            ln2b + (size_t)l * DMODEL, Nn, DFF);
    }
}